// Round 1
// baseline (6835.329 us; speedup 1.0000x reference)
//
#include <hip/hip_runtime.h>
#include <math.h>

#define NH 16
#define NKV 4
#define HD 128
#define DIM 2048

// ---------------- GEMM: C[M,N] = A[M,K] @ W[N,K]^T (all row-major, fp32) ----
#define BM 64
#define BN 64
#define BK 16

__global__ __launch_bounds__(256) void gemm_xwt(const float* __restrict__ A,
                                                const float* __restrict__ W,
                                                float* __restrict__ C,
                                                int M, int N, int K) {
    __shared__ float As[BK][BM + 4];
    __shared__ float Ws[BK][BN + 4];
    const int tid = threadIdx.x;
    const int bm = blockIdx.x * BM;
    const int bn = blockIdx.y * BN;
    const int tx = tid & 15;      // n micro-tile
    const int ty = tid >> 4;      // m micro-tile
    const int lr = tid >> 2;      // loader row 0..63
    const int lk = (tid & 3) * 4; // loader k offset (float4)

    float acc[4][4] = {};

    for (int k0 = 0; k0 < K; k0 += BK) {
        float4 a4 = *(const float4*)(A + (size_t)(bm + lr) * K + k0 + lk);
        float4 w4 = *(const float4*)(W + (size_t)(bn + lr) * K + k0 + lk);
        As[lk + 0][lr] = a4.x; As[lk + 1][lr] = a4.y;
        As[lk + 2][lr] = a4.z; As[lk + 3][lr] = a4.w;
        Ws[lk + 0][lr] = w4.x; Ws[lk + 1][lr] = w4.y;
        Ws[lk + 2][lr] = w4.z; Ws[lk + 3][lr] = w4.w;
        __syncthreads();
#pragma unroll
        for (int kk = 0; kk < BK; kk++) {
            float4 av = *(const float4*)&As[kk][ty * 4];
            float4 wv = *(const float4*)&Ws[kk][tx * 4];
            float a[4] = {av.x, av.y, av.z, av.w};
            float w[4] = {wv.x, wv.y, wv.z, wv.w};
#pragma unroll
            for (int i = 0; i < 4; i++)
#pragma unroll
                for (int j = 0; j < 4; j++)
                    acc[i][j] = fmaf(a[i], w[j], acc[i][j]);
        }
        __syncthreads();
    }
#pragma unroll
    for (int i = 0; i < 4; i++) {
        float4 o = make_float4(acc[i][0], acc[i][1], acc[i][2], acc[i][3]);
        *(float4*)(C + (size_t)(bm + ty * 4 + i) * N + bn + tx * 4) = o;
    }
}

// ------------- RMSNorm + RoPE + q_gain, in place on q and k -----------------
// grid: B*T*(NH+NKV) blocks, 128 threads. hh<NH -> q head, else kv head.
__global__ __launch_bounds__(128) void norm_rope(float* __restrict__ q,
                                                 float* __restrict__ k,
                                                 const float* __restrict__ q_gain,
                                                 int T, double base) {
    const int bid = blockIdx.x;
    const int hh = bid % (NH + NKV);
    const int bt = bid / (NH + NKV);
    const int t = bt % T;
    const int tid = threadIdx.x;

    const bool isq = hh < NH;
    float* ptr = isq ? (q + ((size_t)bt * NH + hh) * HD)
                     : (k + ((size_t)bt * NKV + (hh - NH)) * HD);

    float val = ptr[tid];

    __shared__ float buf[128];
    __shared__ float nrm[128];
    buf[tid] = val * val;
    __syncthreads();
    for (int off = 64; off > 0; off >>= 1) {
        if (tid < off) buf[tid] += buf[tid + off];
        __syncthreads();
    }
    const float scale = rsqrtf(buf[0] * (1.0f / HD) + 1.1920928955078125e-07f);
    nrm[tid] = val * scale;
    __syncthreads();

    const int j = tid & 63;
    const float inv_freq = (float)pow(base, -(double)j / 64.0);
    const float fr = (float)t * inv_freq;
    const float c = cosf(fr);
    const float s = sinf(fr);
    const float x1 = nrm[j];
    const float x2 = nrm[j + 64];
    float out = (tid < 64) ? (x1 * c + x2 * s) : (x2 * c - x1 * s);
    if (isq) out *= q_gain[hh];
    ptr[tid] = out;
}

// ------------- causal GQA attention, one block per (b, h, t) ----------------
__global__ __launch_bounds__(256) void attn_kernel(const float* __restrict__ q,
                                                   const float* __restrict__ k,
                                                   const float* __restrict__ v,
                                                   float* __restrict__ y,
                                                   int T) {
    const int bid = blockIdx.x;
    const int t = bid % T;
    const int bh = bid / T;
    const int h = bh % NH;
    const int b = bh / NH;
    const int kv = h / (NH / NKV);
    const int tid = threadIdx.x;

    __shared__ float qs[HD];
    __shared__ float sc[2048];
    __shared__ float red[256];
    __shared__ float yred[HD];

    const size_t bt = (size_t)b * T + t;
    if (tid < HD) qs[tid] = q[(bt * NH + h) * HD + tid];
    __syncthreads();

    const float* kbase = k + ((size_t)b * T * NKV + kv) * HD;
    const float* vbase0 = v + ((size_t)b * T * NKV + kv) * HD;

    float lmax = -INFINITY;
    for (int s = tid; s <= t; s += 256) {
        const float4* kr = (const float4*)(kbase + (size_t)s * (NKV * HD));
        float dot = 0.0f;
#pragma unroll 8
        for (int d4 = 0; d4 < HD / 4; d4++) {
            float4 kk4 = kr[d4];
            float4 q4 = *(const float4*)&qs[d4 * 4];
            dot = fmaf(q4.x, kk4.x, dot);
            dot = fmaf(q4.y, kk4.y, dot);
            dot = fmaf(q4.z, kk4.z, dot);
            dot = fmaf(q4.w, kk4.w, dot);
        }
        float sv = dot * 0.08838834764831843f; // 1/sqrt(128)
        sc[s] = sv;
        lmax = fmaxf(lmax, sv);
    }

    red[tid] = lmax;
    __syncthreads();
    for (int off = 128; off > 0; off >>= 1) {
        if (tid < off) red[tid] = fmaxf(red[tid], red[tid + off]);
        __syncthreads();
    }
    const float m = red[0];
    __syncthreads();

    float lsum = 0.0f;
    for (int s = tid; s <= t; s += 256) {
        float e = expf(sc[s] - m);
        sc[s] = e;
        lsum += e;
    }
    red[tid] = lsum;
    __syncthreads();
    for (int off = 128; off > 0; off >>= 1) {
        if (tid < off) red[tid] += red[tid + off];
        __syncthreads();
    }
    const float inv_l = 1.0f / red[0];
    __syncthreads();

    // PV: d = tid%128, two s-partitions combined via LDS
    const int d = tid & (HD - 1);
    const int half = tid >> 7;
    const float* vbase = vbase0 + d;
    float acc = 0.0f;
    for (int s = half; s <= t; s += 2) {
        acc = fmaf(sc[s], vbase[(size_t)s * (NKV * HD)], acc);
    }
    if (half) yred[d] = acc;
    __syncthreads();
    if (!half) {
        y[(bt * NH + h) * HD + d] = (acc + yred[d]) * inv_l;
    }
}

// ---------------------------------------------------------------------------
extern "C" void kernel_launch(void* const* d_in, const int* in_sizes, int n_in,
                              void* d_out, int out_size, void* d_ws, size_t ws_size,
                              hipStream_t stream) {
    const float* x      = (const float*)d_in[0];
    const float* Wq     = (const float*)d_in[1];
    const float* Wk     = (const float*)d_in[2];
    const float* Wv     = (const float*)d_in[3];
    const float* Wp     = (const float*)d_in[4];
    const float* q_gain = (const float*)d_in[5];
    float* out = (float*)d_out;

    const int B = 2;
    const int BT = in_sizes[0] / DIM;      // B*T = 4096
    const int T = BT / B;                  // 2048
    const int KD = NKV * HD;               // 512

    float* ws = (float*)d_ws;
    float* qb = ws;                               // BT*DIM
    float* kb = qb + (size_t)BT * DIM;            // BT*KD
    float* vb = kb + (size_t)BT * KD;             // BT*KD
    float* yb = vb + (size_t)BT * KD;             // BT*DIM

    // rope base (double, host)
    double base = 10000.0;
    if (T > 1024) base = 10000.0 * pow((double)T / 1024.0, 128.0 / 126.0);

    // 1-3: QKV projections
    gemm_xwt<<<dim3(BT / BM, DIM / BN), 256, 0, stream>>>(x, Wq, qb, BT, DIM, DIM);
    gemm_xwt<<<dim3(BT / BM, KD / BN), 256, 0, stream>>>(x, Wk, kb, BT, KD, DIM);
    gemm_xwt<<<dim3(BT / BM, KD / BN), 256, 0, stream>>>(x, Wv, vb, BT, KD, DIM);

    // 4: RMSNorm + RoPE + gain (in place on qb, kb)
    norm_rope<<<BT * (NH + NKV), 128, 0, stream>>>(qb, kb, q_gain, T, base);

    // 5: attention
    attn_kernel<<<B * NH * T, 256, 0, stream>>>(qb, kb, vb, yb, T);

    // 6: output projection
    gemm_xwt<<<dim3(BT / BM, DIM / BN), 256, 0, stream>>>(yb, Wp, out, BT, DIM, DIM);
}

// Round 2
// 1750.187 us; speedup vs baseline: 3.9055x; 3.9055x over previous
//
#include <hip/hip_runtime.h>
#include <math.h>

#define NH 16
#define NKV 4
#define HD 128
#define DIM 2048
#define GQ 4   // NH/NKV

using bf16x8 = __attribute__((ext_vector_type(8))) short;
using f32x4  = __attribute__((ext_vector_type(4))) float;

__device__ inline short f2bf(float f) {
    unsigned u = __builtin_bit_cast(unsigned, f);
    return (short)((u + 0x7FFFu + ((u >> 16) & 1u)) >> 16);
}

// ---------------- GEMM: C[M,N] = A[M,K] @ W[N,K]^T (all row-major, fp32) ----
#define BM 64
#define BN 64
#define BK 16

__global__ __launch_bounds__(256) void gemm_xwt(const float* __restrict__ A,
                                                const float* __restrict__ W,
                                                float* __restrict__ C,
                                                int M, int N, int K) {
    __shared__ float As[BK][BM + 4];
    __shared__ float Ws[BK][BN + 4];
    const int tid = threadIdx.x;
    const int bm = blockIdx.x * BM;
    const int bn = blockIdx.y * BN;
    const int tx = tid & 15;
    const int ty = tid >> 4;
    const int lr = tid >> 2;
    const int lk = (tid & 3) * 4;

    float acc[4][4] = {};

    for (int k0 = 0; k0 < K; k0 += BK) {
        float4 a4 = *(const float4*)(A + (size_t)(bm + lr) * K + k0 + lk);
        float4 w4 = *(const float4*)(W + (size_t)(bn + lr) * K + k0 + lk);
        As[lk + 0][lr] = a4.x; As[lk + 1][lr] = a4.y;
        As[lk + 2][lr] = a4.z; As[lk + 3][lr] = a4.w;
        Ws[lk + 0][lr] = w4.x; Ws[lk + 1][lr] = w4.y;
        Ws[lk + 2][lr] = w4.z; Ws[lk + 3][lr] = w4.w;
        __syncthreads();
#pragma unroll
        for (int kk = 0; kk < BK; kk++) {
            float4 av = *(const float4*)&As[kk][ty * 4];
            float4 wv = *(const float4*)&Ws[kk][tx * 4];
            float a[4] = {av.x, av.y, av.z, av.w};
            float w[4] = {wv.x, wv.y, wv.z, wv.w};
#pragma unroll
            for (int i = 0; i < 4; i++)
#pragma unroll
                for (int j = 0; j < 4; j++)
                    acc[i][j] = fmaf(a[i], w[j], acc[i][j]);
        }
        __syncthreads();
    }
#pragma unroll
    for (int i = 0; i < 4; i++) {
        float4 o = make_float4(acc[i][0], acc[i][1], acc[i][2], acc[i][3]);
        *(float4*)(C + (size_t)(bm + ty * 4 + i) * N + bn + tx * 4) = o;
    }
}

// ------------- RMSNorm + RoPE + q_gain, in place on q and k -----------------
__global__ __launch_bounds__(128) void norm_rope(float* __restrict__ q,
                                                 float* __restrict__ k,
                                                 const float* __restrict__ q_gain,
                                                 int T, double base) {
    const int bid = blockIdx.x;
    const int hh = bid % (NH + NKV);
    const int bt = bid / (NH + NKV);
    const int t = bt % T;
    const int tid = threadIdx.x;

    const bool isq = hh < NH;
    float* ptr = isq ? (q + ((size_t)bt * NH + hh) * HD)
                     : (k + ((size_t)bt * NKV + (hh - NH)) * HD);

    float val = ptr[tid];

    __shared__ float buf[128];
    __shared__ float nrm[128];
    buf[tid] = val * val;
    __syncthreads();
    for (int off = 64; off > 0; off >>= 1) {
        if (tid < off) buf[tid] += buf[tid + off];
        __syncthreads();
    }
    const float scale = rsqrtf(buf[0] * (1.0f / HD) + 1.1920928955078125e-07f);
    nrm[tid] = val * scale;
    __syncthreads();

    const int j = tid & 63;
    const float inv_freq = (float)pow(base, -(double)j / 64.0);
    const float fr = (float)t * inv_freq;
    const float c = cosf(fr);
    const float s = sinf(fr);
    const float x1 = nrm[j];
    const float x2 = nrm[j + 64];
    float out = (tid < 64) ? (x1 * c + x2 * s) : (x2 * c - x1 * s);
    if (isq) out *= q_gain[hh];
    ptr[tid] = out;
}

// ------------- flash attention, bf16 MFMA, 64-q-tile per block --------------
#define QT 64
#define SK 64
#define KP (HD + 8)    // Ks pitch (shorts) = 136
#define VP (SK + 8)    // Vt pitch (shorts) = 72
#define SP (SK + 1)    // Sb pitch (floats) = 65
#define PP (SK + 8)    // Pb pitch (shorts) = 72

__global__ __launch_bounds__(256) void flash_attn(const float* __restrict__ q,
                                                  const float* __restrict__ k,
                                                  const float* __restrict__ v,
                                                  float* __restrict__ y, int T) {
    __shared__ short Ks[SK * KP];
    __shared__ short Vt[HD * VP];
    __shared__ float Sb[QT * SP];
    __shared__ short Pb[QT * PP];
    __shared__ float redmax[4 * QT];
    __shared__ float redsum[4 * QT];
    __shared__ float mrow[QT];
    __shared__ float lrow[QT];
    __shared__ float arow[QT];

    const int tid = threadIdx.x;
    const int wave = tid >> 6;
    const int lane = tid & 63;
    const int l16 = lane & 15;
    const int quad = lane >> 4;

    const int bid = blockIdx.x;
    const int nqt = T / QT;
    const int qt = bid % nqt;
    const int h  = (bid / nqt) % NH;
    const int b  = bid / (nqt * NH);
    const int kv = h / GQ;
    const int q0 = qt * QT;

    if (tid < QT) { mrow[tid] = -1e30f; lrow[tid] = 0.0f; }

    // Q fragments (A-layout), 1/sqrt(HD) folded in
    bf16x8 qf[4];
    {
        const int row = q0 + wave * 16 + l16;
        const float* qp = q + ((size_t)(b * T + row) * NH + h) * HD;
        const float sc = 0.08838834764831843f;
#pragma unroll
        for (int ks = 0; ks < 4; ks++) {
            const float* p = qp + ks * 32 + quad * 8;
#pragma unroll
            for (int j = 0; j < 8; j++) qf[ks][j] = f2bf(p[j] * sc);
        }
    }

    f32x4 of[8];
#pragma unroll
    for (int i = 0; i < 8; i++) of[i] = (f32x4){0.f, 0.f, 0.f, 0.f};

    const float* kbase = k + ((size_t)b * T * NKV + kv) * HD;
    const float* vbase = v + ((size_t)b * T * NKV + kv) * HD;

    for (int s0 = 0; s0 <= q0; s0 += SK) {
        __syncthreads();  // previous iteration's readers done
        // stage K tile (row-major) and V tile (transposed) as bf16
        for (int i = tid; i < SK * 32; i += 256) {
            const int r = i >> 5;
            const int c4 = (i & 31) * 4;
            const size_t grow = (size_t)(s0 + r) * (NKV * HD);
            float4 kk = *(const float4*)(kbase + grow + c4);
            float4 vv = *(const float4*)(vbase + grow + c4);
            short* kd = &Ks[r * KP + c4];
            kd[0] = f2bf(kk.x); kd[1] = f2bf(kk.y);
            kd[2] = f2bf(kk.z); kd[3] = f2bf(kk.w);
            Vt[(c4 + 0) * VP + r] = f2bf(vv.x);
            Vt[(c4 + 1) * VP + r] = f2bf(vv.y);
            Vt[(c4 + 2) * VP + r] = f2bf(vv.z);
            Vt[(c4 + 3) * VP + r] = f2bf(vv.w);
        }
        __syncthreads();

        // S = Q K^T for this wave's 16 rows x 64 cols
        f32x4 sf[4];
#pragma unroll
        for (int ct = 0; ct < 4; ct++) sf[ct] = (f32x4){0.f, 0.f, 0.f, 0.f};
#pragma unroll
        for (int ks = 0; ks < 4; ks++) {
#pragma unroll
            for (int ct = 0; ct < 4; ct++) {
                bf16x8 kf = *(const bf16x8*)&Ks[(ct * 16 + l16) * KP + ks * 32 + quad * 8];
                sf[ct] = __builtin_amdgcn_mfma_f32_16x16x32_bf16(qf[ks], kf, sf[ct], 0, 0, 0);
            }
        }
#pragma unroll
        for (int ct = 0; ct < 4; ct++)
#pragma unroll
            for (int r = 0; r < 4; r++)
                Sb[(wave * 16 + quad * 4 + r) * SP + ct * 16 + l16] = sf[ct][r];
        __syncthreads();

        // online softmax: 4 threads per row, 16 cols each
        {
            const int row = tid & 63;
            const int part = tid >> 6;
            const bool diag = (s0 == q0);
            float sv[16];
            float lm = -1e30f;
#pragma unroll
            for (int c = 0; c < 16; c++) {
                float x = Sb[row * SP + part * 16 + c];
                if (diag && (part * 16 + c > row)) x = -1e30f;
                sv[c] = x;
                lm = fmaxf(lm, x);
            }
            redmax[part * QT + row] = lm;
            __syncthreads();
            const float tm = fmaxf(fmaxf(redmax[row], redmax[QT + row]),
                                   fmaxf(redmax[2 * QT + row], redmax[3 * QT + row]));
            const float mprev = mrow[row];
            const float mnew = fmaxf(mprev, tm);
            const float alpha = __expf(mprev - mnew);
            float ls = 0.0f;
            short pt[16] __attribute__((aligned(16)));
#pragma unroll
            for (int c = 0; c < 16; c++) {
                float e = __expf(sv[c] - mnew);
                ls += e;
                pt[c] = f2bf(e);
            }
            *(int4*)&Pb[row * PP + part * 16] = ((int4*)pt)[0];
            *(int4*)&Pb[row * PP + part * 16 + 8] = ((int4*)pt)[1];
            redsum[part * QT + row] = ls;
            __syncthreads();
            if (part == 0) {
                const float s4 = redsum[row] + redsum[QT + row] +
                                 redsum[2 * QT + row] + redsum[3 * QT + row];
                lrow[row] = alpha * lrow[row] + s4;
                mrow[row] = mnew;
                arow[row] = alpha;
            }
        }
        __syncthreads();

        // O = alpha*O + P V
        {
            float al[4];
#pragma unroll
            for (int r = 0; r < 4; r++) al[r] = arow[wave * 16 + quad * 4 + r];
#pragma unroll
            for (int dt = 0; dt < 8; dt++)
#pragma unroll
                for (int r = 0; r < 4; r++) of[dt][r] *= al[r];
#pragma unroll
            for (int ks = 0; ks < 2; ks++) {
                bf16x8 pf = *(const bf16x8*)&Pb[(wave * 16 + l16) * PP + ks * 32 + quad * 8];
#pragma unroll
                for (int dt = 0; dt < 8; dt++) {
                    bf16x8 vf = *(const bf16x8*)&Vt[(dt * 16 + l16) * VP + ks * 32 + quad * 8];
                    of[dt] = __builtin_amdgcn_mfma_f32_16x16x32_bf16(pf, vf, of[dt], 0, 0, 0);
                }
            }
        }
    }

    __syncthreads();
#pragma unroll
    for (int r = 0; r < 4; r++) {
        const int row = wave * 16 + quad * 4 + r;
        const float inv = 1.0f / lrow[row];
        float* yp = y + ((size_t)(b * T + q0 + row) * NH + h) * HD + l16;
#pragma unroll
        for (int dt = 0; dt < 8; dt++)
            yp[dt * 16] = of[dt][r] * inv;
    }
}

// ---------------------------------------------------------------------------
extern "C" void kernel_launch(void* const* d_in, const int* in_sizes, int n_in,
                              void* d_out, int out_size, void* d_ws, size_t ws_size,
                              hipStream_t stream) {
    const float* x      = (const float*)d_in[0];
    const float* Wq     = (const float*)d_in[1];
    const float* Wk     = (const float*)d_in[2];
    const float* Wv     = (const float*)d_in[3];
    const float* Wp     = (const float*)d_in[4];
    const float* q_gain = (const float*)d_in[5];
    float* out = (float*)d_out;

    const int B = 2;
    const int BT = in_sizes[0] / DIM;      // B*T = 4096
    const int T = BT / B;                  // 2048
    const int KD = NKV * HD;               // 512

    float* ws = (float*)d_ws;
    float* qb = ws;                               // BT*DIM
    float* kb = qb + (size_t)BT * DIM;            // BT*KD
    float* vb = kb + (size_t)BT * KD;             // BT*KD
    float* yb = vb + (size_t)BT * KD;             // BT*DIM

    double base = 10000.0;
    if (T > 1024) base = 10000.0 * pow((double)T / 1024.0, 128.0 / 126.0);

    gemm_xwt<<<dim3(BT / BM, DIM / BN), 256, 0, stream>>>(x, Wq, qb, BT, DIM, DIM);
    gemm_xwt<<<dim3(BT / BM, KD / BN), 256, 0, stream>>>(x, Wk, kb, BT, KD, DIM);
    gemm_xwt<<<dim3(BT / BM, KD / BN), 256, 0, stream>>>(x, Wv, vb, BT, KD, DIM);

    norm_rope<<<BT * (NH + NKV), 128, 0, stream>>>(qb, kb, q_gain, T, base);

    flash_attn<<<B * NH * (T / QT), 256, 0, stream>>>(qb, kb, vb, yb, T);

    gemm_xwt<<<dim3(BT / BM, DIM / BN), 256, 0, stream>>>(yb, Wp, out, BT, DIM, DIM);
}

// Round 3
// 779.424 us; speedup vs baseline: 8.7697x; 2.2455x over previous
//
#include <hip/hip_runtime.h>
#include <math.h>

#define NH 16
#define NKV 4
#define HD 128
#define DIM 2048
#define GQ 4   // NH/NKV

typedef unsigned short u16;
using bf16x8 = __attribute__((ext_vector_type(8))) short;
using f32x4  = __attribute__((ext_vector_type(4))) float;

__device__ inline short f2bf(float f) {
    unsigned u = __builtin_bit_cast(unsigned, f);
    return (short)((u + 0x7FFFu + ((u >> 16) & 1u)) >> 16);
}

#define ASYNC_LOAD16(g, l)                                                        \
    __builtin_amdgcn_global_load_lds(                                             \
        (const __attribute__((address_space(1))) unsigned*)(g),                   \
        (__attribute__((address_space(3))) unsigned*)(l), 16, 0, 0)

// ---------------- fp32 -> bf16 convert (vectorized) -------------------------
__global__ __launch_bounds__(256) void cvt_bf16(const float* __restrict__ src,
                                                u16* __restrict__ dst, int n4) {
    int i = blockIdx.x * 256 + threadIdx.x;
    if (i < n4) {
        float4 f = ((const float4*)src)[i];
        ushort4 o;
        o.x = (u16)f2bf(f.x); o.y = (u16)f2bf(f.y);
        o.z = (u16)f2bf(f.z); o.w = (u16)f2bf(f.w);
        ((ushort4*)dst)[i] = o;
    }
}

// ------- GEMM (m97 structure): C[M,N] fp32 = A16[M,K] @ W16[N,K]^T ----------
// 128x128 tile, BK=32, 4 waves of 64x64, global_load_lds width-16 staging.
#define GTK 32

__global__ __launch_bounds__(256) void gemm_bf16(const u16* __restrict__ A,
                                                 const u16* __restrict__ W,
                                                 float* __restrict__ C,
                                                 int M, int N, int K) {
    __shared__ u16 As[128 * GTK];
    __shared__ u16 Bs[128 * GTK];
    const int tid = threadIdx.x;
    const int wave = tid >> 6;
    const int lane = tid & 63;
    const int l16 = lane & 15;
    const int quad = lane >> 4;
    const int wm = wave >> 1;
    const int wn = wave & 1;
    const int m0 = blockIdx.x * 128;
    const int n0 = blockIdx.y * 128;

    const int srow = lane >> 2;          // 0..15 within a 16-row issue
    const int scol = (lane & 3) * 8;     // bf16 element offset

    f32x4 acc[4][4];
#pragma unroll
    for (int i = 0; i < 4; i++)
#pragma unroll
        for (int j = 0; j < 4; j++) acc[i][j] = (f32x4){0.f, 0.f, 0.f, 0.f};

    for (int k0 = 0; k0 < K; k0 += GTK) {
        __syncthreads();
#pragma unroll
        for (int j = 0; j < 2; j++) {
            const int rb = wave * 32 + j * 16;
            const u16* ga = A + (size_t)(m0 + rb + srow) * K + k0 + scol;
            const u16* gb = W + (size_t)(n0 + rb + srow) * K + k0 + scol;
            ASYNC_LOAD16(ga, &As[rb * GTK]);
            ASYNC_LOAD16(gb, &Bs[rb * GTK]);
        }
        __syncthreads();

        bf16x8 af[4], bfr[4];
#pragma unroll
        for (int mt = 0; mt < 4; mt++)
            af[mt] = *(const bf16x8*)&As[(wm * 64 + mt * 16 + l16) * GTK + quad * 8];
#pragma unroll
        for (int nt = 0; nt < 4; nt++)
            bfr[nt] = *(const bf16x8*)&Bs[(wn * 64 + nt * 16 + l16) * GTK + quad * 8];
#pragma unroll
        for (int mt = 0; mt < 4; mt++)
#pragma unroll
            for (int nt = 0; nt < 4; nt++)
                acc[mt][nt] = __builtin_amdgcn_mfma_f32_16x16x32_bf16(
                    af[mt], bfr[nt], acc[mt][nt], 0, 0, 0);
    }

#pragma unroll
    for (int mt = 0; mt < 4; mt++)
#pragma unroll
        for (int nt = 0; nt < 4; nt++)
#pragma unroll
            for (int r = 0; r < 4; r++)
                C[(size_t)(m0 + wm * 64 + mt * 16 + quad * 4 + r) * N +
                  n0 + wn * 64 + nt * 16 + l16] = acc[mt][nt][r];
}

// ------------- RMSNorm + RoPE + q_gain, in place on q and k -----------------
__global__ __launch_bounds__(128) void norm_rope(float* __restrict__ q,
                                                 float* __restrict__ k,
                                                 const float* __restrict__ q_gain,
                                                 int T, double base) {
    const int bid = blockIdx.x;
    const int hh = bid % (NH + NKV);
    const int bt = bid / (NH + NKV);
    const int t = bt % T;
    const int tid = threadIdx.x;

    const bool isq = hh < NH;
    float* ptr = isq ? (q + ((size_t)bt * NH + hh) * HD)
                     : (k + ((size_t)bt * NKV + (hh - NH)) * HD);

    float val = ptr[tid];

    __shared__ float buf[128];
    __shared__ float nrm[128];
    buf[tid] = val * val;
    __syncthreads();
    for (int off = 64; off > 0; off >>= 1) {
        if (tid < off) buf[tid] += buf[tid + off];
        __syncthreads();
    }
    const float scale = rsqrtf(buf[0] * (1.0f / HD) + 1.1920928955078125e-07f);
    nrm[tid] = val * scale;
    __syncthreads();

    const int j = tid & 63;
    const float inv_freq = (float)pow(base, -(double)j / 64.0);
    const float fr = (float)t * inv_freq;
    const float c = cosf(fr);
    const float s = sinf(fr);
    const float x1 = nrm[j];
    const float x2 = nrm[j + 64];
    float out = (tid < 64) ? (x1 * c + x2 * s) : (x2 * c - x1 * s);
    if (isq) out *= q_gain[hh];
    ptr[tid] = out;
}

// ------------- flash attention, bf16 MFMA, 64-q-tile per block --------------
#define QT 64
#define SK 64
#define KP (HD + 8)
#define VP (SK + 8)
#define SP (SK + 1)
#define PP (SK + 8)

__global__ __launch_bounds__(256) void flash_attn(const float* __restrict__ q,
                                                  const float* __restrict__ k,
                                                  const float* __restrict__ v,
                                                  u16* __restrict__ y, int T) {
    __shared__ short Ks[SK * KP];
    __shared__ short Vt[HD * VP];
    __shared__ float Sb[QT * SP];
    __shared__ short Pb[QT * PP];
    __shared__ float redmax[4 * QT];
    __shared__ float redsum[4 * QT];
    __shared__ float mrow[QT];
    __shared__ float lrow[QT];
    __shared__ float arow[QT];

    const int tid = threadIdx.x;
    const int wave = tid >> 6;
    const int lane = tid & 63;
    const int l16 = lane & 15;
    const int quad = lane >> 4;

    const int bid = blockIdx.x;
    const int nqt = T / QT;
    const int qt = bid % nqt;
    const int h  = (bid / nqt) % NH;
    const int b  = bid / (nqt * NH);
    const int kv = h / GQ;
    const int q0 = qt * QT;

    if (tid < QT) { mrow[tid] = -1e30f; lrow[tid] = 0.0f; }

    bf16x8 qf[4];
    {
        const int row = q0 + wave * 16 + l16;
        const float* qp = q + ((size_t)(b * T + row) * NH + h) * HD;
        const float sc = 0.08838834764831843f;
#pragma unroll
        for (int ks = 0; ks < 4; ks++) {
            const float* p = qp + ks * 32 + quad * 8;
#pragma unroll
            for (int j = 0; j < 8; j++) qf[ks][j] = f2bf(p[j] * sc);
        }
    }

    f32x4 of[8];
#pragma unroll
    for (int i = 0; i < 8; i++) of[i] = (f32x4){0.f, 0.f, 0.f, 0.f};

    const float* kbase = k + ((size_t)b * T * NKV + kv) * HD;
    const float* vbase = v + ((size_t)b * T * NKV + kv) * HD;

    for (int s0 = 0; s0 <= q0; s0 += SK) {
        __syncthreads();
        for (int i = tid; i < SK * 32; i += 256) {
            const int r = i >> 5;
            const int c4 = (i & 31) * 4;
            const size_t grow = (size_t)(s0 + r) * (NKV * HD);
            float4 kk = *(const float4*)(kbase + grow + c4);
            float4 vv = *(const float4*)(vbase + grow + c4);
            short* kd = &Ks[r * KP + c4];
            kd[0] = f2bf(kk.x); kd[1] = f2bf(kk.y);
            kd[2] = f2bf(kk.z); kd[3] = f2bf(kk.w);
            Vt[(c4 + 0) * VP + r] = f2bf(vv.x);
            Vt[(c4 + 1) * VP + r] = f2bf(vv.y);
            Vt[(c4 + 2) * VP + r] = f2bf(vv.z);
            Vt[(c4 + 3) * VP + r] = f2bf(vv.w);
        }
        __syncthreads();

        f32x4 sf[4];
#pragma unroll
        for (int ct = 0; ct < 4; ct++) sf[ct] = (f32x4){0.f, 0.f, 0.f, 0.f};
#pragma unroll
        for (int ks = 0; ks < 4; ks++) {
#pragma unroll
            for (int ct = 0; ct < 4; ct++) {
                bf16x8 kf = *(const bf16x8*)&Ks[(ct * 16 + l16) * KP + ks * 32 + quad * 8];
                sf[ct] = __builtin_amdgcn_mfma_f32_16x16x32_bf16(qf[ks], kf, sf[ct], 0, 0, 0);
            }
        }
#pragma unroll
        for (int ct = 0; ct < 4; ct++)
#pragma unroll
            for (int r = 0; r < 4; r++)
                Sb[(wave * 16 + quad * 4 + r) * SP + ct * 16 + l16] = sf[ct][r];
        __syncthreads();

        {
            const int row = tid & 63;
            const int part = tid >> 6;
            const bool diag = (s0 == q0);
            float sv[16];
            float lm = -1e30f;
#pragma unroll
            for (int c = 0; c < 16; c++) {
                float x = Sb[row * SP + part * 16 + c];
                if (diag && (part * 16 + c > row)) x = -1e30f;
                sv[c] = x;
                lm = fmaxf(lm, x);
            }
            redmax[part * QT + row] = lm;
            __syncthreads();
            const float tm = fmaxf(fmaxf(redmax[row], redmax[QT + row]),
                                   fmaxf(redmax[2 * QT + row], redmax[3 * QT + row]));
            const float mprev = mrow[row];
            const float mnew = fmaxf(mprev, tm);
            const float alpha = __expf(mprev - mnew);
            float ls = 0.0f;
            short pt[16] __attribute__((aligned(16)));
#pragma unroll
            for (int c = 0; c < 16; c++) {
                float e = __expf(sv[c] - mnew);
                ls += e;
                pt[c] = f2bf(e);
            }
            *(int4*)&Pb[row * PP + part * 16] = ((int4*)pt)[0];
            *(int4*)&Pb[row * PP + part * 16 + 8] = ((int4*)pt)[1];
            redsum[part * QT + row] = ls;
            __syncthreads();
            if (part == 0) {
                const float s4 = redsum[row] + redsum[QT + row] +
                                 redsum[2 * QT + row] + redsum[3 * QT + row];
                lrow[row] = alpha * lrow[row] + s4;
                mrow[row] = mnew;
                arow[row] = alpha;
            }
        }
        __syncthreads();

        {
            float al[4];
#pragma unroll
            for (int r = 0; r < 4; r++) al[r] = arow[wave * 16 + quad * 4 + r];
#pragma unroll
            for (int dt = 0; dt < 8; dt++)
#pragma unroll
                for (int r = 0; r < 4; r++) of[dt][r] *= al[r];
#pragma unroll
            for (int ks = 0; ks < 2; ks++) {
                bf16x8 pf = *(const bf16x8*)&Pb[(wave * 16 + l16) * PP + ks * 32 + quad * 8];
#pragma unroll
                for (int dt = 0; dt < 8; dt++) {
                    bf16x8 vf = *(const bf16x8*)&Vt[(dt * 16 + l16) * VP + ks * 32 + quad * 8];
                    of[dt] = __builtin_amdgcn_mfma_f32_16x16x32_bf16(pf, vf, of[dt], 0, 0, 0);
                }
            }
        }
    }

    __syncthreads();
#pragma unroll
    for (int r = 0; r < 4; r++) {
        const int row = wave * 16 + quad * 4 + r;
        const float inv = 1.0f / lrow[row];
        u16* yp = y + ((size_t)(b * T + q0 + row) * NH + h) * HD + l16;
#pragma unroll
        for (int dt = 0; dt < 8; dt++)
            yp[dt * 16] = (u16)f2bf(of[dt][r] * inv);
    }
}

// ---------------------------------------------------------------------------
extern "C" void kernel_launch(void* const* d_in, const int* in_sizes, int n_in,
                              void* d_out, int out_size, void* d_ws, size_t ws_size,
                              hipStream_t stream) {
    const float* x      = (const float*)d_in[0];
    const float* Wq     = (const float*)d_in[1];
    const float* Wk     = (const float*)d_in[2];
    const float* Wv     = (const float*)d_in[3];
    const float* Wp     = (const float*)d_in[4];
    const float* q_gain = (const float*)d_in[5];
    float* out = (float*)d_out;

    const int B = 2;
    const int BT = in_sizes[0] / DIM;      // 4096
    const int T = BT / B;                  // 2048
    const int KD = NKV * HD;               // 512

    // workspace layout (with aliasing): ~76 MB
    float* qb   = (float*)d_ws;                       // BT*DIM     fp32
    float* kb   = qb + (size_t)BT * DIM;              // BT*KD      fp32
    float* vb   = kb + (size_t)BT * KD;               // BT*KD      fp32
    u16*   x16  = (u16*)(vb + (size_t)BT * KD);       // BT*DIM     bf16  (later y16)
    u16*   w1   = x16 + (size_t)BT * DIM;             // DIM*DIM    bf16  (Wq16 then Wp16)
    u16*   wk16 = w1 + (size_t)DIM * DIM;             // KD*DIM     bf16
    u16*   wv16 = wk16 + (size_t)KD * DIM;            // KD*DIM     bf16
    u16*   y16  = x16;                                // alias: x16 dead after QKV GEMMs

    double base = 10000.0;
    if (T > 1024) base = 10000.0 * pow((double)T / 1024.0, 128.0 / 126.0);

    const int nx4  = BT * DIM / 4;
    const int nwq4 = DIM * DIM / 4;
    const int nwk4 = KD * DIM / 4;

    cvt_bf16<<<(nx4 + 255) / 256, 256, 0, stream>>>(x, x16, nx4);
    cvt_bf16<<<(nwq4 + 255) / 256, 256, 0, stream>>>(Wq, w1, nwq4);
    cvt_bf16<<<(nwk4 + 255) / 256, 256, 0, stream>>>(Wk, wk16, nwk4);
    cvt_bf16<<<(nwk4 + 255) / 256, 256, 0, stream>>>(Wv, wv16, nwk4);

    gemm_bf16<<<dim3(BT / 128, DIM / 128), 256, 0, stream>>>(x16, w1, qb, BT, DIM, DIM);
    gemm_bf16<<<dim3(BT / 128, KD / 128), 256, 0, stream>>>(x16, wk16, kb, BT, KD, DIM);
    gemm_bf16<<<dim3(BT / 128, KD / 128), 256, 0, stream>>>(x16, wv16, vb, BT, KD, DIM);

    norm_rope<<<BT * (NH + NKV), 128, 0, stream>>>(qb, kb, q_gain, T, base);

    cvt_bf16<<<(nwq4 + 255) / 256, 256, 0, stream>>>(Wp, w1, nwq4);  // w1 now Wp16

    flash_attn<<<B * NH * (T / QT), 256, 0, stream>>>(qb, kb, vb, y16, T);

    gemm_bf16<<<dim3(BT / 128, DIM / 128), 256, 0, stream>>>(y16, w1, out, BT, DIM, DIM);
}

// Round 4
// 534.558 us; speedup vs baseline: 12.7869x; 1.4581x over previous
//
#include <hip/hip_runtime.h>
#include <math.h>

#define NH 16
#define NKV 4
#define HD 128
#define DIM 2048
#define GQ 4   // NH/NKV

typedef unsigned short u16;
using bf16x8 = __attribute__((ext_vector_type(8))) short;
using f16x4  = __attribute__((ext_vector_type(4))) _Float16;
using f32x4  = __attribute__((ext_vector_type(4))) float;

__device__ inline short f2bf(float f) {
    unsigned u = __builtin_bit_cast(unsigned, f);
    return (short)((u + 0x7FFFu + ((u >> 16) & 1u)) >> 16);
}
__device__ inline u16 f2h(float f) {
    _Float16 h = (_Float16)f;
    return __builtin_bit_cast(u16, h);
}

#define ASYNC_LOAD16(g, l)                                                        \
    __builtin_amdgcn_global_load_lds(                                             \
        (const __attribute__((address_space(1))) unsigned*)(g),                   \
        (__attribute__((address_space(3))) unsigned*)(l), 16, 0, 0)

// ---------------- fp32 -> bf16 convert (vectorized) -------------------------
__global__ __launch_bounds__(256) void cvt_bf16(const float* __restrict__ src,
                                                u16* __restrict__ dst, int n4) {
    int i = blockIdx.x * 256 + threadIdx.x;
    if (i < n4) {
        float4 f = ((const float4*)src)[i];
        ushort4 o;
        o.x = (u16)f2bf(f.x); o.y = (u16)f2bf(f.y);
        o.z = (u16)f2bf(f.z); o.w = (u16)f2bf(f.w);
        ((ushort4*)dst)[i] = o;
    }
}

// ------- GEMM (m97 structure): C[M,N] fp32 = A16[M,K] @ W16[N,K]^T ----------
#define GTK 32

__global__ __launch_bounds__(256) void gemm_bf16(const u16* __restrict__ A,
                                                 const u16* __restrict__ W,
                                                 float* __restrict__ C,
                                                 int M, int N, int K) {
    __shared__ u16 As[128 * GTK];
    __shared__ u16 Bs[128 * GTK];
    const int tid = threadIdx.x;
    const int wave = tid >> 6;
    const int lane = tid & 63;
    const int l16 = lane & 15;
    const int quad = lane >> 4;
    const int wm = wave >> 1;
    const int wn = wave & 1;
    const int m0 = blockIdx.x * 128;
    const int n0 = blockIdx.y * 128;

    const int srow = lane >> 2;
    const int scol = (lane & 3) * 8;

    f32x4 acc[4][4];
#pragma unroll
    for (int i = 0; i < 4; i++)
#pragma unroll
        for (int j = 0; j < 4; j++) acc[i][j] = (f32x4){0.f, 0.f, 0.f, 0.f};

    for (int k0 = 0; k0 < K; k0 += GTK) {
        __syncthreads();
#pragma unroll
        for (int j = 0; j < 2; j++) {
            const int rb = wave * 32 + j * 16;
            const u16* ga = A + (size_t)(m0 + rb + srow) * K + k0 + scol;
            const u16* gb = W + (size_t)(n0 + rb + srow) * K + k0 + scol;
            ASYNC_LOAD16(ga, &As[rb * GTK]);
            ASYNC_LOAD16(gb, &Bs[rb * GTK]);
        }
        __syncthreads();

        bf16x8 af[4], bfr[4];
#pragma unroll
        for (int mt = 0; mt < 4; mt++)
            af[mt] = *(const bf16x8*)&As[(wm * 64 + mt * 16 + l16) * GTK + quad * 8];
#pragma unroll
        for (int nt = 0; nt < 4; nt++)
            bfr[nt] = *(const bf16x8*)&Bs[(wn * 64 + nt * 16 + l16) * GTK + quad * 8];
#pragma unroll
        for (int mt = 0; mt < 4; mt++)
#pragma unroll
            for (int nt = 0; nt < 4; nt++)
                acc[mt][nt] = __builtin_amdgcn_mfma_f32_16x16x32_bf16(
                    af[mt], bfr[nt], acc[mt][nt], 0, 0, 0);
    }

#pragma unroll
    for (int mt = 0; mt < 4; mt++)
#pragma unroll
        for (int nt = 0; nt < 4; nt++)
#pragma unroll
            for (int r = 0; r < 4; r++)
                C[(size_t)(m0 + wm * 64 + mt * 16 + quad * 4 + r) * N +
                  n0 + wn * 64 + nt * 16 + l16] = acc[mt][nt][r];
}

// --- RMSNorm + RoPE + q_gain; emits q16 (scaled by gain/sqrt(HD)) and k16 ---
__global__ __launch_bounds__(128) void norm_rope(const float* __restrict__ q,
                                                 const float* __restrict__ k,
                                                 u16* __restrict__ q16,
                                                 u16* __restrict__ k16,
                                                 const float* __restrict__ q_gain,
                                                 int T, double base) {
    const int bid = blockIdx.x;
    const int hh = bid % (NH + NKV);
    const int bt = bid / (NH + NKV);
    const int t = bt % T;
    const int tid = threadIdx.x;

    const bool isq = hh < NH;
    const float* ptr = isq ? (q + ((size_t)bt * NH + hh) * HD)
                           : (k + ((size_t)bt * NKV + (hh - NH)) * HD);

    float val = ptr[tid];

    __shared__ float buf[128];
    __shared__ float nrm[128];
    buf[tid] = val * val;
    __syncthreads();
    for (int off = 64; off > 0; off >>= 1) {
        if (tid < off) buf[tid] += buf[tid + off];
        __syncthreads();
    }
    const float scale = rsqrtf(buf[0] * (1.0f / HD) + 1.1920928955078125e-07f);
    nrm[tid] = val * scale;
    __syncthreads();

    const int j = tid & 63;
    const float inv_freq = (float)pow(base, -(double)j / 64.0);
    const float fr = (float)t * inv_freq;
    const float c = cosf(fr);
    const float s = sinf(fr);
    const float x1 = nrm[j];
    const float x2 = nrm[j + 64];
    float out = (tid < 64) ? (x1 * c + x2 * s) : (x2 * c - x1 * s);
    if (isq) {
        out *= q_gain[hh] * 0.08838834764831843f;  // fold 1/sqrt(HD)
        q16[((size_t)bt * NH + hh) * HD + tid] = (u16)f2bf(out);
    } else {
        k16[((size_t)bt * NKV + (hh - NH)) * HD + tid] = (u16)f2bf(out);
    }
}

// --------- V transpose: vb fp32 [b][t][kv][d] -> vt16 f16 [b*kv][d][T] ------
__global__ __launch_bounds__(256) void vtrans(const float* __restrict__ v,
                                              u16* __restrict__ vt, int T) {
    __shared__ float ts[64][65];
    const int tid = threadIdx.x;
    const int t0 = blockIdx.x * 64;
    const int d0 = blockIdx.y * 64;
    const int bk = blockIdx.z;                 // b*NKV + kv
    const int b = bk >> 2, kv = bk & 3;

    {
        const int r = tid >> 2;
        const int c0 = (tid & 3) * 16;
        const float* src = v + ((size_t)(b * T + t0 + r) * NKV + kv) * HD + d0 + c0;
#pragma unroll
        for (int jj = 0; jj < 4; jj++) {
            float4 f = *(const float4*)(src + jj * 4);
            ts[r][c0 + jj * 4 + 0] = f.x;
            ts[r][c0 + jj * 4 + 1] = f.y;
            ts[r][c0 + jj * 4 + 2] = f.z;
            ts[r][c0 + jj * 4 + 3] = f.w;
        }
    }
    __syncthreads();
    {
        const int d = tid >> 2;
        const int tc = (tid & 3) * 16;
        u16 tmp[16] __attribute__((aligned(16)));
#pragma unroll
        for (int jj = 0; jj < 16; jj++)
            tmp[jj] = f2h(ts[tc + jj][d]);
        u16* dst = vt + ((size_t)bk * HD + d0 + d) * T + t0 + tc;
        *(int4*)dst = ((int4*)tmp)[0];
        *(int4*)(dst + 8) = ((int4*)tmp)[1];
    }
}

// ------ flash attention, S^T formulation, register softmax ------------------
// S^T = K Q^T (bf16 16x16x32), O^T = V^T P^T (f16 16x16x16, P^T C-frag == B-frag)
#define QT 64
#define SK 64
#define KP 136   // Ks pitch in shorts
#define VP 68    // Vt pitch in shorts

__global__ __launch_bounds__(256) void flash2(const u16* __restrict__ q16,
                                              const u16* __restrict__ k16,
                                              const u16* __restrict__ vt16,
                                              u16* __restrict__ y16, int T) {
    __shared__ u16 Ks[SK * KP];
    __shared__ u16 Vt[HD * VP];

    const int tid = threadIdx.x;
    const int wave = tid >> 6;
    const int lane = tid & 63;
    const int l16 = lane & 15;
    const int quad = lane >> 4;

    const int bid = blockIdx.x;
    const int bh = bid & 31;          // b*NH + h (fast dim -> spreads over CUs)
    const int qt = bid >> 5;          // q-tile (slow dim -> balances causal work)
    const int h = bh & 15;
    const int b = bh >> 4;
    const int kv = h / GQ;
    const int q0 = qt * QT;

    // Q^T B-fragments (scale already folded in)
    bf16x8 qf[4];
    {
        const int row = q0 + wave * 16 + l16;
        const u16* qp = q16 + ((size_t)(b * T + row) * NH + h) * HD;
#pragma unroll
        for (int kc = 0; kc < 4; kc++)
            qf[kc] = *(const bf16x8*)(qp + kc * 32 + quad * 8);
    }

    f32x4 of[8];
#pragma unroll
    for (int i = 0; i < 8; i++) of[i] = (f32x4){0.f, 0.f, 0.f, 0.f};
    float m_i = -1e30f, l_i = 0.0f;

    const u16* kg = k16 + ((size_t)b * T * NKV + kv) * HD;     // row stride 512
    const u16* vg = vt16 + (size_t)(b * NKV + kv) * HD * T;    // row stride T

    const int qglob = q0 + wave * 16 + l16;

    for (int s0 = 0; s0 <= q0; s0 += SK) {
        __syncthreads();
        // stage K tile: 64 rows x 128 bf16 (16B chunks)
        for (int idx = tid; idx < SK * 16; idx += 256) {
            const int r = idx >> 4, ch = idx & 15;
            *(int4*)&Ks[r * KP + ch * 8] =
                *(const int4*)(kg + (size_t)(s0 + r) * (NKV * HD) + ch * 8);
        }
        // stage V^T tile: 128 rows x 64 f16 (16B chunks)
        for (int idx = tid; idx < HD * 8; idx += 256) {
            const int d = idx >> 3, ch = idx & 7;
            *(int4*)&Vt[d * VP + ch * 8] =
                *(const int4*)(vg + (size_t)d * T + s0 + ch * 8);
        }
        __syncthreads();

        // S^T = K Q^T : rows s (4 tiles of 16), cols q (this wave's 16)
        f32x4 sf[4];
#pragma unroll
        for (int st = 0; st < 4; st++) sf[st] = (f32x4){0.f, 0.f, 0.f, 0.f};
#pragma unroll
        for (int kc = 0; kc < 4; kc++)
#pragma unroll
            for (int st = 0; st < 4; st++) {
                bf16x8 kf = *(const bf16x8*)&Ks[(st * 16 + l16) * KP + kc * 32 + quad * 8];
                sf[st] = __builtin_amdgcn_mfma_f32_16x16x32_bf16(kf, qf[kc], sf[st], 0, 0, 0);
            }

        // causal mask (only the diagonal tile needs it)
        if (s0 == q0) {
#pragma unroll
            for (int st = 0; st < 4; st++)
#pragma unroll
                for (int r = 0; r < 4; r++)
                    if (s0 + st * 16 + quad * 4 + r > qglob) sf[st][r] = -1e30f;
        }

        // register online softmax over s (16 in-lane + quads via shfl)
        float tm = -1e30f;
#pragma unroll
        for (int st = 0; st < 4; st++)
#pragma unroll
            for (int r = 0; r < 4; r++) tm = fmaxf(tm, sf[st][r]);
        tm = fmaxf(tm, __shfl_xor(tm, 16));
        tm = fmaxf(tm, __shfl_xor(tm, 32));

        const float mnew = fmaxf(m_i, tm);
        const float alpha = __expf(m_i - mnew);
        m_i = mnew;

        f16x4 pf[4];
        float ls = 0.0f;
#pragma unroll
        for (int st = 0; st < 4; st++)
#pragma unroll
            for (int r = 0; r < 4; r++) {
                float e = __expf(sf[st][r] - mnew);
                ls += e;
                pf[st][r] = (_Float16)e;
            }
        ls += __shfl_xor(ls, 16);
        ls += __shfl_xor(ls, 32);
        l_i = alpha * l_i + ls;

#pragma unroll
        for (int dt = 0; dt < 8; dt++)
#pragma unroll
            for (int r = 0; r < 4; r++) of[dt][r] *= alpha;

        // O^T += V^T P^T   (P^T C-frag is directly the f16 B-frag)
#pragma unroll
        for (int st = 0; st < 4; st++)
#pragma unroll
            for (int dt = 0; dt < 8; dt++) {
                f16x4 vf = *(const f16x4*)&Vt[(dt * 16 + l16) * VP + st * 16 + quad * 4];
                of[dt] = __builtin_amdgcn_mfma_f32_16x16x16f16(vf, pf[st], of[dt], 0, 0, 0);
            }
    }

    const float inv = 1.0f / l_i;
    u16* yp = y16 + ((size_t)(b * T + qglob) * NH + h) * HD + quad * 4;
#pragma unroll
    for (int dt = 0; dt < 8; dt++) {
        ushort4 o;
        o.x = (u16)f2bf(of[dt][0] * inv);
        o.y = (u16)f2bf(of[dt][1] * inv);
        o.z = (u16)f2bf(of[dt][2] * inv);
        o.w = (u16)f2bf(of[dt][3] * inv);
        *(ushort4*)(yp + dt * 16) = o;
    }
}

// ---------------------------------------------------------------------------
extern "C" void kernel_launch(void* const* d_in, const int* in_sizes, int n_in,
                              void* d_out, int out_size, void* d_ws, size_t ws_size,
                              hipStream_t stream) {
    const float* x      = (const float*)d_in[0];
    const float* Wq     = (const float*)d_in[1];
    const float* Wk     = (const float*)d_in[2];
    const float* Wv     = (const float*)d_in[3];
    const float* Wp     = (const float*)d_in[4];
    const float* q_gain = (const float*)d_in[5];
    float* out = (float*)d_out;

    const int B = 2;
    const int BT = in_sizes[0] / DIM;      // 4096
    const int T = BT / B;                  // 2048
    const int KD = NKV * HD;               // 512

    // workspace (76 MB, with aliasing):
    float* qb   = (float*)d_ws;                       // BT*DIM fp32   (later y16)
    float* kb   = qb + (size_t)BT * DIM;              // BT*KD  fp32   (later vt16)
    float* vb   = kb + (size_t)BT * KD;               // BT*KD  fp32
    u16*   x16  = (u16*)(vb + (size_t)BT * KD);       // BT*DIM bf16   (later q16)
    u16*   w1   = x16 + (size_t)BT * DIM;             // DIM*DIM bf16  (Wq16 then Wp16)
    u16*   wk16 = w1 + (size_t)DIM * DIM;             // KD*DIM bf16   (later k16, spans wv16)
    u16*   wv16 = wk16 + (size_t)KD * DIM;            // KD*DIM bf16
    u16*   q16  = x16;        // x16 dead after QKV GEMMs
    u16*   k16  = wk16;       // wk16+wv16 (4MB) dead after QKV GEMMs
    u16*   vt16 = (u16*)kb;   // kb dead after norm_rope
    u16*   y16  = (u16*)qb;   // qb dead after norm_rope

    double base = 10000.0;
    if (T > 1024) base = 10000.0 * pow((double)T / 1024.0, 128.0 / 126.0);

    const int nx4  = BT * DIM / 4;
    const int nwq4 = DIM * DIM / 4;
    const int nwk4 = KD * DIM / 4;

    cvt_bf16<<<(nx4 + 255) / 256, 256, 0, stream>>>(x, x16, nx4);
    cvt_bf16<<<(nwq4 + 255) / 256, 256, 0, stream>>>(Wq, w1, nwq4);
    cvt_bf16<<<(nwk4 + 255) / 256, 256, 0, stream>>>(Wk, wk16, nwk4);
    cvt_bf16<<<(nwk4 + 255) / 256, 256, 0, stream>>>(Wv, wv16, nwk4);

    gemm_bf16<<<dim3(BT / 128, DIM / 128), 256, 0, stream>>>(x16, w1, qb, BT, DIM, DIM);
    gemm_bf16<<<dim3(BT / 128, KD / 128), 256, 0, stream>>>(x16, wk16, kb, BT, KD, DIM);
    gemm_bf16<<<dim3(BT / 128, KD / 128), 256, 0, stream>>>(x16, wv16, vb, BT, KD, DIM);

    norm_rope<<<BT * (NH + NKV), 128, 0, stream>>>(qb, kb, q16, k16, q_gain, T, base);

    vtrans<<<dim3(T / 64, HD / 64, B * NKV), 256, 0, stream>>>(vb, vt16, T);

    cvt_bf16<<<(nwq4 + 255) / 256, 256, 0, stream>>>(Wp, w1, nwq4);  // w1 = Wp16

    flash2<<<32 * (T / QT), 256, 0, stream>>>(q16, k16, vt16, y16, T);

    gemm_bf16<<<dim3(BT / 128, DIM / 128), 256, 0, stream>>>(y16, w1, out, BT, DIM, DIM);
}

// Round 5
// 389.328 us; speedup vs baseline: 17.5567x; 1.3730x over previous
//
#include <hip/hip_runtime.h>
#include <math.h>

#define NH 16
#define NKV 4
#define HD 128
#define DIM 2048
#define GQ 4   // NH/NKV
#define EPS 1.1920928955078125e-07f

typedef unsigned short u16;
using bf16x8 = __attribute__((ext_vector_type(8))) short;
using f16x4  = __attribute__((ext_vector_type(4))) _Float16;
using f32x4  = __attribute__((ext_vector_type(4))) float;

__device__ inline short f2bf(float f) {
    unsigned u = __builtin_bit_cast(unsigned, f);
    return (short)((u + 0x7FFFu + ((u >> 16) & 1u)) >> 16);
}
__device__ inline u16 f2h(float f) {
    _Float16 h = (_Float16)f;
    return __builtin_bit_cast(u16, h);
}

#define ASYNC_LOAD16(g, l)                                                        \
    __builtin_amdgcn_global_load_lds(                                             \
        (const __attribute__((address_space(1))) unsigned*)(g),                   \
        (__attribute__((address_space(3))) unsigned*)(l), 16, 0, 0)

// ---------------- fp32 -> bf16 convert (vectorized) -------------------------
__global__ __launch_bounds__(256) void cvt_bf16(const float* __restrict__ src,
                                                u16* __restrict__ dst, int n4) {
    int i = blockIdx.x * 256 + threadIdx.x;
    if (i < n4) {
        float4 f = ((const float4*)src)[i];
        ushort4 o;
        o.x = (u16)f2bf(f.x); o.y = (u16)f2bf(f.y);
        o.z = (u16)f2bf(f.z); o.w = (u16)f2bf(f.w);
        ((ushort4*)dst)[i] = o;
    }
}

// ---------------- RoPE cos/sin tables: [T][64] ------------------------------
__global__ __launch_bounds__(64) void rope_tab(float* __restrict__ ct,
                                               float* __restrict__ st,
                                               double base) {
    const int t = blockIdx.x;
    const int j = threadIdx.x;
    const float inv_freq = (float)pow(base, -(double)j / 64.0);
    const float fr = (float)t * inv_freq;
    ct[t * 64 + j] = cosf(fr);
    st[t * 64 + j] = sinf(fr);
}

// ------- GEMM (m97 structure): C[M,N] fp32 = A16[M,K] @ W16[N,K]^T ----------
#define GTK 32

__global__ __launch_bounds__(256) void gemm_bf16(const u16* __restrict__ A,
                                                 const u16* __restrict__ W,
                                                 float* __restrict__ C,
                                                 int M, int N, int K) {
    __shared__ u16 As[128 * GTK];
    __shared__ u16 Bs[128 * GTK];
    const int tid = threadIdx.x;
    const int wave = tid >> 6;
    const int lane = tid & 63;
    const int l16 = lane & 15;
    const int quad = lane >> 4;
    const int wm = wave >> 1;
    const int wn = wave & 1;
    const int m0 = blockIdx.x * 128;
    const int n0 = blockIdx.y * 128;

    const int srow = lane >> 2;
    const int scol = (lane & 3) * 8;

    f32x4 acc[4][4];
#pragma unroll
    for (int i = 0; i < 4; i++)
#pragma unroll
        for (int j = 0; j < 4; j++) acc[i][j] = (f32x4){0.f, 0.f, 0.f, 0.f};

    for (int k0 = 0; k0 < K; k0 += GTK) {
        __syncthreads();
#pragma unroll
        for (int j = 0; j < 2; j++) {
            const int rb = wave * 32 + j * 16;
            const u16* ga = A + (size_t)(m0 + rb + srow) * K + k0 + scol;
            const u16* gb = W + (size_t)(n0 + rb + srow) * K + k0 + scol;
            ASYNC_LOAD16(ga, &As[rb * GTK]);
            ASYNC_LOAD16(gb, &Bs[rb * GTK]);
        }
        __syncthreads();

        bf16x8 af[4], bfr[4];
#pragma unroll
        for (int mt = 0; mt < 4; mt++)
            af[mt] = *(const bf16x8*)&As[(wm * 64 + mt * 16 + l16) * GTK + quad * 8];
#pragma unroll
        for (int nt = 0; nt < 4; nt++)
            bfr[nt] = *(const bf16x8*)&Bs[(wn * 64 + nt * 16 + l16) * GTK + quad * 8];
#pragma unroll
        for (int mt = 0; mt < 4; mt++)
#pragma unroll
            for (int nt = 0; nt < 4; nt++)
                acc[mt][nt] = __builtin_amdgcn_mfma_f32_16x16x32_bf16(
                    af[mt], bfr[nt], acc[mt][nt], 0, 0, 0);
    }

#pragma unroll
    for (int mt = 0; mt < 4; mt++)
#pragma unroll
        for (int nt = 0; nt < 4; nt++)
#pragma unroll
            for (int r = 0; r < 4; r++)
                C[(size_t)(m0 + wm * 64 + mt * 16 + quad * 4 + r) * N +
                  n0 + wn * 64 + nt * 16 + l16] = acc[mt][nt][r];
}

// ------- fused QKV GEMM: N=3072 (q 0..2047, k 2048..2559, v 2560..3071) -----
// Row-split waves: wave owns rows wave*32..+31, all 128 cols of the n-tile.
// Epilogue: q/k -> RMSNorm + RoPE (+gain) -> bf16; v -> f16 transposed.
__global__ __launch_bounds__(256) void gemm_qkv(const u16* __restrict__ A,
                                                const u16* __restrict__ W,
                                                u16* __restrict__ q16,
                                                u16* __restrict__ k16,
                                                u16* __restrict__ vt16,
                                                const float* __restrict__ ctab,
                                                const float* __restrict__ stab,
                                                const float* __restrict__ q_gain,
                                                int T) {
    __shared__ u16 As[128 * GTK];
    __shared__ u16 Bs[128 * GTK];
    const int tid = threadIdx.x;
    const int wave = tid >> 6;
    const int lane = tid & 63;
    const int l16 = lane & 15;
    const int quad = lane >> 4;
    const int m0 = blockIdx.x * 128;
    const int n0 = blockIdx.y * 128;
    const int K = DIM;

    const int srow = lane >> 2;
    const int scol = (lane & 3) * 8;

    f32x4 acc[2][8];
#pragma unroll
    for (int i = 0; i < 2; i++)
#pragma unroll
        for (int j = 0; j < 8; j++) acc[i][j] = (f32x4){0.f, 0.f, 0.f, 0.f};

    for (int k0 = 0; k0 < K; k0 += GTK) {
        __syncthreads();
#pragma unroll
        for (int j = 0; j < 2; j++) {
            const int rb = wave * 32 + j * 16;
            const u16* ga = A + (size_t)(m0 + rb + srow) * K + k0 + scol;
            const u16* gb = W + (size_t)(n0 + rb + srow) * K + k0 + scol;
            ASYNC_LOAD16(ga, &As[rb * GTK]);
            ASYNC_LOAD16(gb, &Bs[rb * GTK]);
        }
        __syncthreads();

        bf16x8 af[2], bfr[8];
#pragma unroll
        for (int mt = 0; mt < 2; mt++)
            af[mt] = *(const bf16x8*)&As[(wave * 32 + mt * 16 + l16) * GTK + quad * 8];
#pragma unroll
        for (int nt = 0; nt < 8; nt++)
            bfr[nt] = *(const bf16x8*)&Bs[(nt * 16 + l16) * GTK + quad * 8];
#pragma unroll
        for (int mt = 0; mt < 2; mt++)
#pragma unroll
            for (int nt = 0; nt < 8; nt++)
                acc[mt][nt] = __builtin_amdgcn_mfma_f32_16x16x32_bf16(
                    af[mt], bfr[nt], acc[mt][nt], 0, 0, 0);
    }

    // ---------------- fused epilogue ----------------
    if (n0 < 2048 + 512) {
        // Q or K head: RMSNorm + RoPE (+ gain for Q)
        const bool isQ = (n0 < 2048);
        const float gval = isQ ? (q_gain[n0 >> 7] * 0.08838834764831843f) : 1.0f;
        // sum of squares per row (in-lane over 8 nt, shfl over l16)
        float ss[2][4];
#pragma unroll
        for (int mt = 0; mt < 2; mt++)
#pragma unroll
            for (int r = 0; r < 4; r++) {
                float s = 0.f;
#pragma unroll
                for (int nt = 0; nt < 8; nt++) {
                    float a = acc[mt][nt][r];
                    s = fmaf(a, a, s);
                }
                s += __shfl_xor(s, 1);
                s += __shfl_xor(s, 2);
                s += __shfl_xor(s, 4);
                s += __shfl_xor(s, 8);
                ss[mt][r] = s;
            }
#pragma unroll
        for (int mt = 0; mt < 2; mt++)
#pragma unroll
            for (int r = 0; r < 4; r++) {
                const float scale = rsqrtf(ss[mt][r] * (1.0f / HD) + EPS) * gval;
                const int m = m0 + wave * 32 + mt * 16 + quad * 4 + r;
                const int t = m & (T - 1);
                const float* ct = ctab + t * 64;
                const float* st = stab + t * 64;
                u16* dst = isQ ? (q16 + (size_t)m * 2048 + n0)
                               : (k16 + (size_t)m * 512 + (n0 - 2048));
#pragma unroll
                for (int nt = 0; nt < 4; nt++) {
                    const int j = nt * 16 + l16;
                    const float c = ct[j], s = st[j];
                    const float x1 = acc[mt][nt][r] * scale;
                    const float x2 = acc[mt][nt + 4][r] * scale;
                    dst[j]      = (u16)f2bf(x1 * c + x2 * s);
                    dst[j + 64] = (u16)f2bf(x2 * c - x1 * s);
                }
            }
    } else {
        // V head: f16, transposed -> vt16[(b*NKV+kv)*HD + d][T]
        const int kvh = (n0 - 2560) >> 7;
#pragma unroll
        for (int mt = 0; mt < 2; mt++) {
            const int mb = m0 + wave * 32 + mt * 16 + quad * 4;
            const int b = mb / 2048;          // T == 2048
            const int t0 = mb & (T - 1);
#pragma unroll
            for (int nt = 0; nt < 8; nt++) {
                const int d = nt * 16 + l16;
                ushort4 o;
                o.x = f2h(acc[mt][nt][0]);
                o.y = f2h(acc[mt][nt][1]);
                o.z = f2h(acc[mt][nt][2]);
                o.w = f2h(acc[mt][nt][3]);
                *(ushort4*)(vt16 + ((size_t)((b * NKV + kvh) * HD + d)) * T + t0) = o;
            }
        }
    }
}

// ------ flash attention, S^T formulation, register softmax ------------------
#define QT 64
#define SK 64
#define KP 136   // Ks pitch in shorts
#define VP 68    // Vt pitch in shorts

__global__ __launch_bounds__(256) void flash2(const u16* __restrict__ q16,
                                              const u16* __restrict__ k16,
                                              const u16* __restrict__ vt16,
                                              u16* __restrict__ y16, int T) {
    __shared__ u16 Ks[SK * KP];
    __shared__ u16 Vt[HD * VP];

    const int tid = threadIdx.x;
    const int wave = tid >> 6;
    const int lane = tid & 63;
    const int l16 = lane & 15;
    const int quad = lane >> 4;

    const int bid = blockIdx.x;
    const int bh = bid & 31;                      // b*NH + h (fast -> spread)
    const int qt = (T / QT - 1) - (bid >> 5);     // LPT: longest blocks first
    const int h = bh & 15;
    const int b = bh >> 4;
    const int kv = h / GQ;
    const int q0 = qt * QT;

    bf16x8 qf[4];
    {
        const int row = q0 + wave * 16 + l16;
        const u16* qp = q16 + ((size_t)(b * T + row) * NH + h) * HD;
#pragma unroll
        for (int kc = 0; kc < 4; kc++)
            qf[kc] = *(const bf16x8*)(qp + kc * 32 + quad * 8);
    }

    f32x4 of[8];
#pragma unroll
    for (int i = 0; i < 8; i++) of[i] = (f32x4){0.f, 0.f, 0.f, 0.f};
    float m_i = -1e30f, l_i = 0.0f;

    const u16* kg = k16 + ((size_t)b * T * NKV + kv) * HD;
    const u16* vg = vt16 + (size_t)(b * NKV + kv) * HD * T;

    const int qglob = q0 + wave * 16 + l16;

    for (int s0 = 0; s0 <= q0; s0 += SK) {
        __syncthreads();
        for (int idx = tid; idx < SK * 16; idx += 256) {
            const int r = idx >> 4, ch = idx & 15;
            *(int4*)&Ks[r * KP + ch * 8] =
                *(const int4*)(kg + (size_t)(s0 + r) * (NKV * HD) + ch * 8);
        }
        for (int idx = tid; idx < HD * 8; idx += 256) {
            const int d = idx >> 3, ch = idx & 7;
            *(int4*)&Vt[d * VP + ch * 8] =
                *(const int4*)(vg + (size_t)d * T + s0 + ch * 8);
        }
        __syncthreads();

        f32x4 sf[4];
#pragma unroll
        for (int st = 0; st < 4; st++) sf[st] = (f32x4){0.f, 0.f, 0.f, 0.f};
#pragma unroll
        for (int kc = 0; kc < 4; kc++)
#pragma unroll
            for (int st = 0; st < 4; st++) {
                bf16x8 kf = *(const bf16x8*)&Ks[(st * 16 + l16) * KP + kc * 32 + quad * 8];
                sf[st] = __builtin_amdgcn_mfma_f32_16x16x32_bf16(kf, qf[kc], sf[st], 0, 0, 0);
            }

        if (s0 == q0) {
#pragma unroll
            for (int st = 0; st < 4; st++)
#pragma unroll
                for (int r = 0; r < 4; r++)
                    if (s0 + st * 16 + quad * 4 + r > qglob) sf[st][r] = -1e30f;
        }

        float tm = -1e30f;
#pragma unroll
        for (int st = 0; st < 4; st++)
#pragma unroll
            for (int r = 0; r < 4; r++) tm = fmaxf(tm, sf[st][r]);
        tm = fmaxf(tm, __shfl_xor(tm, 16));
        tm = fmaxf(tm, __shfl_xor(tm, 32));

        const float mnew = fmaxf(m_i, tm);
        const float alpha = __expf(m_i - mnew);
        m_i = mnew;

        f16x4 pf[4];
        float ls = 0.0f;
#pragma unroll
        for (int st = 0; st < 4; st++)
#pragma unroll
            for (int r = 0; r < 4; r++) {
                float e = __expf(sf[st][r] - mnew);
                ls += e;
                pf[st][r] = (_Float16)e;
            }
        ls += __shfl_xor(ls, 16);
        ls += __shfl_xor(ls, 32);
        l_i = alpha * l_i + ls;

#pragma unroll
        for (int dt = 0; dt < 8; dt++)
#pragma unroll
            for (int r = 0; r < 4; r++) of[dt][r] *= alpha;

#pragma unroll
        for (int st = 0; st < 4; st++)
#pragma unroll
            for (int dt = 0; dt < 8; dt++) {
                f16x4 vf = *(const f16x4*)&Vt[(dt * 16 + l16) * VP + st * 16 + quad * 4];
                of[dt] = __builtin_amdgcn_mfma_f32_16x16x16f16(vf, pf[st], of[dt], 0, 0, 0);
            }
    }

    const float inv = 1.0f / l_i;
    u16* yp = y16 + ((size_t)(b * T + qglob) * NH + h) * HD + quad * 4;
#pragma unroll
    for (int dt = 0; dt < 8; dt++) {
        ushort4 o;
        o.x = (u16)f2bf(of[dt][0] * inv);
        o.y = (u16)f2bf(of[dt][1] * inv);
        o.z = (u16)f2bf(of[dt][2] * inv);
        o.w = (u16)f2bf(of[dt][3] * inv);
        *(ushort4*)(yp + dt * 16) = o;
    }
}

// ---------------------------------------------------------------------------
extern "C" void kernel_launch(void* const* d_in, const int* in_sizes, int n_in,
                              void* d_out, int out_size, void* d_ws, size_t ws_size,
                              hipStream_t stream) {
    const float* x      = (const float*)d_in[0];
    const float* Wq     = (const float*)d_in[1];
    const float* Wk     = (const float*)d_in[2];
    const float* Wv     = (const float*)d_in[3];
    const float* Wp     = (const float*)d_in[4];
    const float* q_gain = (const float*)d_in[5];
    float* out = (float*)d_out;

    const int B = 2;
    const int BT = in_sizes[0] / DIM;      // 4096
    const int T = BT / B;                  // 2048
    const int KD = NKV * HD;               // 512

    // workspace (~64 MB):
    u16* x16   = (u16*)d_ws;                        // BT*DIM        (later y16)
    u16* wqkv  = x16 + (size_t)BT * DIM;            // 3072*DIM
    u16* wp16  = wqkv + (size_t)3072 * DIM;         // DIM*DIM
    u16* q16   = wp16 + (size_t)DIM * DIM;          // BT*DIM
    u16* k16   = q16 + (size_t)BT * DIM;            // BT*KD
    u16* vt16  = k16 + (size_t)BT * KD;             // BT*KD
    float* ctab = (float*)(vt16 + (size_t)BT * KD); // T*64
    float* stab = ctab + (size_t)T * 64;            // T*64
    u16* y16   = x16;                               // alias: x16 dead after gemm_qkv

    double base = 10000.0;
    if (T > 1024) base = 10000.0 * pow((double)T / 1024.0, 128.0 / 126.0);

    const int nx4  = BT * DIM / 4;
    const int nwq4 = DIM * DIM / 4;
    const int nwk4 = KD * DIM / 4;

    cvt_bf16<<<(nx4 + 255) / 256, 256, 0, stream>>>(x, x16, nx4);
    cvt_bf16<<<(nwq4 + 255) / 256, 256, 0, stream>>>(Wq, wqkv, nwq4);
    cvt_bf16<<<(nwk4 + 255) / 256, 256, 0, stream>>>(Wk, wqkv + (size_t)2048 * DIM, nwk4);
    cvt_bf16<<<(nwk4 + 255) / 256, 256, 0, stream>>>(Wv, wqkv + (size_t)2560 * DIM, nwk4);
    cvt_bf16<<<(nwq4 + 255) / 256, 256, 0, stream>>>(Wp, wp16, nwq4);
    rope_tab<<<T, 64, 0, stream>>>(ctab, stab, base);

    gemm_qkv<<<dim3(BT / 128, 3072 / 128), 256, 0, stream>>>(
        x16, wqkv, q16, k16, vt16, ctab, stab, q_gain, T);

    flash2<<<32 * (T / QT), 256, 0, stream>>>(q16, k16, vt16, y16, T);

    gemm_bf16<<<dim3(BT / 128, DIM / 128), 256, 0, stream>>>(y16, wp16, out, BT, DIM, DIM);
}

// Round 7
// 377.270 us; speedup vs baseline: 18.1179x; 1.0320x over previous
//
#include <hip/hip_runtime.h>
#include <math.h>

#define NH 16
#define NKV 4
#define HD 128
#define DIM 2048
#define GQ 4   // NH/NKV
#define EPS 1.1920928955078125e-07f

typedef unsigned short u16;
using bf16x8 = __attribute__((ext_vector_type(8))) short;
using f16x4  = __attribute__((ext_vector_type(4))) _Float16;
using f16x8  = __attribute__((ext_vector_type(8))) _Float16;
using f32x4  = __attribute__((ext_vector_type(4))) float;

__device__ inline float fast_exp2(float x) { return __builtin_amdgcn_exp2f(x); }

__device__ inline short f2bf(float f) {
    unsigned u = __builtin_bit_cast(unsigned, f);
    return (short)((u + 0x7FFFu + ((u >> 16) & 1u)) >> 16);
}
__device__ inline u16 f2h(float f) {
    _Float16 h = (_Float16)f;
    return __builtin_bit_cast(u16, h);
}

#define ASYNC_LOAD16(g, l)                                                        \
    __builtin_amdgcn_global_load_lds(                                             \
        (const __attribute__((address_space(1))) unsigned*)(g),                   \
        (__attribute__((address_space(3))) unsigned*)(l), 16, 0, 0)

// ---------------- fp32 -> bf16 convert (vectorized) -------------------------
__global__ __launch_bounds__(256) void cvt_bf16(const float* __restrict__ src,
                                                u16* __restrict__ dst, int n4) {
    int i = blockIdx.x * 256 + threadIdx.x;
    if (i < n4) {
        float4 f = ((const float4*)src)[i];
        ushort4 o;
        o.x = (u16)f2bf(f.x); o.y = (u16)f2bf(f.y);
        o.z = (u16)f2bf(f.z); o.w = (u16)f2bf(f.w);
        ((ushort4*)dst)[i] = o;
    }
}

// ---------------- RoPE cos/sin tables: [T][64] ------------------------------
__global__ __launch_bounds__(64) void rope_tab(float* __restrict__ ct,
                                               float* __restrict__ st,
                                               double base) {
    const int t = blockIdx.x;
    const int j = threadIdx.x;
    const float inv_freq = (float)pow(base, -(double)j / 64.0);
    const float fr = (float)t * inv_freq;
    ct[t * 64 + j] = cosf(fr);
    st[t * 64 + j] = sinf(fr);
}

// ------- GEMM (m97 structure): C[M,N] fp32 = A16[M,K] @ W16[N,K]^T ----------
#define GTK 32

__global__ __launch_bounds__(256) void gemm_bf16(const u16* __restrict__ A,
                                                 const u16* __restrict__ W,
                                                 float* __restrict__ C,
                                                 int M, int N, int K) {
    __shared__ u16 As[128 * GTK];
    __shared__ u16 Bs[128 * GTK];
    const int tid = threadIdx.x;
    const int wave = tid >> 6;
    const int lane = tid & 63;
    const int l16 = lane & 15;
    const int quad = lane >> 4;
    const int wm = wave >> 1;
    const int wn = wave & 1;
    const int m0 = blockIdx.x * 128;
    const int n0 = blockIdx.y * 128;

    const int srow = lane >> 2;
    const int scol = (lane & 3) * 8;

    f32x4 acc[4][4];
#pragma unroll
    for (int i = 0; i < 4; i++)
#pragma unroll
        for (int j = 0; j < 4; j++) acc[i][j] = (f32x4){0.f, 0.f, 0.f, 0.f};

    for (int k0 = 0; k0 < K; k0 += GTK) {
        __syncthreads();
#pragma unroll
        for (int j = 0; j < 2; j++) {
            const int rb = wave * 32 + j * 16;
            const u16* ga = A + (size_t)(m0 + rb + srow) * K + k0 + scol;
            const u16* gb = W + (size_t)(n0 + rb + srow) * K + k0 + scol;
            ASYNC_LOAD16(ga, &As[rb * GTK]);
            ASYNC_LOAD16(gb, &Bs[rb * GTK]);
        }
        __syncthreads();

        bf16x8 af[4], bfr[4];
#pragma unroll
        for (int mt = 0; mt < 4; mt++)
            af[mt] = *(const bf16x8*)&As[(wm * 64 + mt * 16 + l16) * GTK + quad * 8];
#pragma unroll
        for (int nt = 0; nt < 4; nt++)
            bfr[nt] = *(const bf16x8*)&Bs[(wn * 64 + nt * 16 + l16) * GTK + quad * 8];
#pragma unroll
        for (int mt = 0; mt < 4; mt++)
#pragma unroll
            for (int nt = 0; nt < 4; nt++)
                acc[mt][nt] = __builtin_amdgcn_mfma_f32_16x16x32_bf16(
                    af[mt], bfr[nt], acc[mt][nt], 0, 0, 0);
    }

#pragma unroll
    for (int mt = 0; mt < 4; mt++)
#pragma unroll
        for (int nt = 0; nt < 4; nt++)
#pragma unroll
            for (int r = 0; r < 4; r++)
                C[(size_t)(m0 + wm * 64 + mt * 16 + quad * 4 + r) * N +
                  n0 + wn * 64 + nt * 16 + l16] = acc[mt][nt][r];
}

// ------- fused QKV GEMM: N=3072 (q 0..2047, k 2048..2559, v 2560..3071) -----
__global__ __launch_bounds__(256) void gemm_qkv(const u16* __restrict__ A,
                                                const u16* __restrict__ W,
                                                u16* __restrict__ q16,
                                                u16* __restrict__ k16,
                                                u16* __restrict__ vt16,
                                                const float* __restrict__ ctab,
                                                const float* __restrict__ stab,
                                                const float* __restrict__ q_gain,
                                                int T) {
    __shared__ u16 As[128 * GTK];
    __shared__ u16 Bs[128 * GTK];
    const int tid = threadIdx.x;
    const int wave = tid >> 6;
    const int lane = tid & 63;
    const int l16 = lane & 15;
    const int quad = lane >> 4;
    const int m0 = blockIdx.x * 128;
    const int n0 = blockIdx.y * 128;
    const int K = DIM;

    const int srow = lane >> 2;
    const int scol = (lane & 3) * 8;

    f32x4 acc[2][8];
#pragma unroll
    for (int i = 0; i < 2; i++)
#pragma unroll
        for (int j = 0; j < 8; j++) acc[i][j] = (f32x4){0.f, 0.f, 0.f, 0.f};

    for (int k0 = 0; k0 < K; k0 += GTK) {
        __syncthreads();
#pragma unroll
        for (int j = 0; j < 2; j++) {
            const int rb = wave * 32 + j * 16;
            const u16* ga = A + (size_t)(m0 + rb + srow) * K + k0 + scol;
            const u16* gb = W + (size_t)(n0 + rb + srow) * K + k0 + scol;
            ASYNC_LOAD16(ga, &As[rb * GTK]);
            ASYNC_LOAD16(gb, &Bs[rb * GTK]);
        }
        __syncthreads();

        bf16x8 af[2], bfr[8];
#pragma unroll
        for (int mt = 0; mt < 2; mt++)
            af[mt] = *(const bf16x8*)&As[(wave * 32 + mt * 16 + l16) * GTK + quad * 8];
#pragma unroll
        for (int nt = 0; nt < 8; nt++)
            bfr[nt] = *(const bf16x8*)&Bs[(nt * 16 + l16) * GTK + quad * 8];
#pragma unroll
        for (int mt = 0; mt < 2; mt++)
#pragma unroll
            for (int nt = 0; nt < 8; nt++)
                acc[mt][nt] = __builtin_amdgcn_mfma_f32_16x16x32_bf16(
                    af[mt], bfr[nt], acc[mt][nt], 0, 0, 0);
    }

    // ---------------- fused epilogue ----------------
    if (n0 < 2048 + 512) {
        const bool isQ = (n0 < 2048);
        // Q: fold gain, 1/sqrt(HD), and log2(e) (flash uses exp2)
        const float gval = isQ ? (q_gain[n0 >> 7] * 0.08838834764831843f * 1.4426950408889634f)
                               : 1.0f;
        float ss[2][4];
#pragma unroll
        for (int mt = 0; mt < 2; mt++)
#pragma unroll
            for (int r = 0; r < 4; r++) {
                float s = 0.f;
#pragma unroll
                for (int nt = 0; nt < 8; nt++) {
                    float a = acc[mt][nt][r];
                    s = fmaf(a, a, s);
                }
                s += __shfl_xor(s, 1);
                s += __shfl_xor(s, 2);
                s += __shfl_xor(s, 4);
                s += __shfl_xor(s, 8);
                ss[mt][r] = s;
            }
#pragma unroll
        for (int mt = 0; mt < 2; mt++)
#pragma unroll
            for (int r = 0; r < 4; r++) {
                const float scale = rsqrtf(ss[mt][r] * (1.0f / HD) + EPS) * gval;
                const int m = m0 + wave * 32 + mt * 16 + quad * 4 + r;
                const int t = m & (T - 1);
                const float* ct = ctab + t * 64;
                const float* st = stab + t * 64;
                u16* dst = isQ ? (q16 + (size_t)m * 2048 + n0)
                               : (k16 + (size_t)m * 512 + (n0 - 2048));
#pragma unroll
                for (int nt = 0; nt < 4; nt++) {
                    const int j = nt * 16 + l16;
                    const float c = ct[j], s = st[j];
                    const float x1 = acc[mt][nt][r] * scale;
                    const float x2 = acc[mt][nt + 4][r] * scale;
                    dst[j]      = (u16)f2bf(x1 * c + x2 * s);
                    dst[j + 64] = (u16)f2bf(x2 * c - x1 * s);
                }
            }
    } else {
        const int kvh = (n0 - 2560) >> 7;
#pragma unroll
        for (int mt = 0; mt < 2; mt++) {
            const int mb = m0 + wave * 32 + mt * 16 + quad * 4;
            const int b = mb / 2048;          // T == 2048
            const int t0 = mb & (T - 1);
#pragma unroll
            for (int nt = 0; nt < 8; nt++) {
                const int d = nt * 16 + l16;
                ushort4 o;
                o.x = f2h(acc[mt][nt][0]);
                o.y = f2h(acc[mt][nt][1]);
                o.z = f2h(acc[mt][nt][2]);
                o.w = f2h(acc[mt][nt][3]);
                *(ushort4*)(vt16 + ((size_t)((b * NKV + kvh) * HD + d)) * T + t0) = o;
            }
        }
    }
}

// ------ flash attention v3: mirror-paired uniform blocks, double-buffered ---
// S^T = K Q^T (bf16 x32); softmax in registers (exp2); O^T = V^T P^T (f16 x16)
// V^T LDS layout s-permuted (pos = quad*16 + st*4 + r) for b128 reads.
#define QT 64
#define SK 64
#define KP 136   // Ks pitch in shorts
#define VPP 72   // Vt pitch in shorts

__global__ __launch_bounds__(256) void flash3(const u16* __restrict__ q16,
                                              const u16* __restrict__ k16,
                                              const u16* __restrict__ vt16,
                                              u16* __restrict__ y16, int T) {
    __shared__ u16 Ks[2][SK * KP];
    __shared__ u16 Vt[2][HD * VPP];

    const int tid = threadIdx.x;
    const int wave = tid >> 6;
    const int lane = tid & 63;
    const int l16 = lane & 15;
    const int quad = lane >> 4;

    const int bid = blockIdx.x;
    const int bh = bid & 31;          // b*NH + h
    const int pr = bid >> 5;          // pair index 0..T/QT/2-1
    const int h = bh & 15;
    const int b = bh >> 4;
    const int kv = h / GQ;

    const u16* kg = k16 + ((size_t)b * T * NKV + kv) * HD;
    const u16* vg = vt16 + (size_t)(b * NKV + kv) * HD * T;

    // staging indices (per-thread, fixed)
    int kr[4], kc_[4], vd[4], vch[4];
#pragma unroll
    for (int j = 0; j < 4; j++) {
        const int idx = tid + j * 256;
        kr[j] = idx >> 4; kc_[j] = (idx & 15) * 8;
        vd[j] = idx >> 3; vch[j] = idx & 7;
    }

    int4 kpre[4], vpre[4];

#pragma unroll
    for (int half = 0; half < 2; half++) {
        const int qt = half ? (T / QT - 1 - pr) : pr;
        const int q0 = qt * QT;
        const int qglob = q0 + wave * 16 + l16;
        const int nts = q0 / SK + 1;

        // Q^T B-fragments (gain, 1/sqrt(HD), log2e folded in)
        bf16x8 qf[4];
        {
            const u16* qp = q16 + ((size_t)(b * T + qglob) * NH + h) * HD;
#pragma unroll
            for (int kc = 0; kc < 4; kc++)
                qf[kc] = *(const bf16x8*)(qp + kc * 32 + quad * 8);
        }

        f32x4 of[8];
#pragma unroll
        for (int i = 0; i < 8; i++) of[i] = (f32x4){0.f, 0.f, 0.f, 0.f};
        float m_i = -1e30f, l_i = 0.0f;

        // preload tile 0
#pragma unroll
        for (int j = 0; j < 4; j++)
            kpre[j] = *(const int4*)(kg + (size_t)kr[j] * (NKV * HD) + kc_[j]);
#pragma unroll
        for (int j = 0; j < 4; j++)
            vpre[j] = *(const int4*)(vg + (size_t)vd[j] * T + vch[j] * 8);

        for (int it = 0; it < nts; it++) {
            const int cur = it & 1;
            __syncthreads();   // all waves done reading buf[cur] (2 iters ago)
            // commit prefetched tile into LDS
#pragma unroll
            for (int j = 0; j < 4; j++)
                *(int4*)&Ks[cur][kr[j] * KP + kc_[j]] = kpre[j];
#pragma unroll
            for (int j = 0; j < 4; j++) {
                const int ch = vch[j];
                u16* row = &Vt[cur][vd[j] * VPP];
                const int p1 = ((2 * ch) & 3) * 16 + (ch >> 1) * 4;
                const int p2 = ((2 * ch + 1) & 3) * 16 + (ch >> 1) * 4;
                *(int2*)&row[p1] = make_int2(vpre[j].x, vpre[j].y);
                *(int2*)&row[p2] = make_int2(vpre[j].z, vpre[j].w);
            }
            __syncthreads();

            // prefetch next tile (loads overlap with compute below)
            if (it + 1 < nts) {
                const int s1 = (it + 1) * SK;
#pragma unroll
                for (int j = 0; j < 4; j++)
                    kpre[j] = *(const int4*)(kg + (size_t)(s1 + kr[j]) * (NKV * HD) + kc_[j]);
#pragma unroll
                for (int j = 0; j < 4; j++)
                    vpre[j] = *(const int4*)(vg + (size_t)vd[j] * T + s1 + vch[j] * 8);
            }

            // S^T = K Q^T
            f32x4 sf[4];
#pragma unroll
            for (int st = 0; st < 4; st++) sf[st] = (f32x4){0.f, 0.f, 0.f, 0.f};
#pragma unroll
            for (int kc = 0; kc < 4; kc++)
#pragma unroll
                for (int st = 0; st < 4; st++) {
                    bf16x8 kf = *(const bf16x8*)&Ks[cur][(st * 16 + l16) * KP + kc * 32 + quad * 8];
                    sf[st] = __builtin_amdgcn_mfma_f32_16x16x32_bf16(kf, qf[kc], sf[st], 0, 0, 0);
                }

            if (it == nts - 1) {  // diagonal tile: causal mask
#pragma unroll
                for (int st = 0; st < 4; st++)
#pragma unroll
                    for (int r = 0; r < 4; r++)
                        if (q0 + st * 16 + quad * 4 + r > qglob) sf[st][r] = -1e30f;
            }

            float tm = -1e30f;
#pragma unroll
            for (int st = 0; st < 4; st++)
#pragma unroll
                for (int r = 0; r < 4; r++) tm = fmaxf(tm, sf[st][r]);
            tm = fmaxf(tm, __shfl_xor(tm, 16));
            tm = fmaxf(tm, __shfl_xor(tm, 32));

            const float mprev = m_i;
            const float mnew = fmaxf(mprev, tm);
            m_i = mnew;
            const float alpha = fast_exp2(mprev - mnew);

            f16x4 pf[4];
            float ls = 0.0f;
#pragma unroll
            for (int st = 0; st < 4; st++)
#pragma unroll
                for (int r = 0; r < 4; r++) {
                    float e = fast_exp2(sf[st][r] - mnew);
                    ls += e;
                    pf[st][r] = (_Float16)e;
                }
            ls += __shfl_xor(ls, 16);
            ls += __shfl_xor(ls, 32);
            l_i = alpha * l_i + ls;

            if (__ballot(mnew > mprev)) {
#pragma unroll
                for (int dt = 0; dt < 8; dt++)
#pragma unroll
                    for (int r = 0; r < 4; r++) of[dt][r] *= alpha;
            }

            // O^T += V^T P^T (b128 V reads: two st-groups per load)
#pragma unroll
            for (int st2 = 0; st2 < 2; st2++)
#pragma unroll
                for (int dt = 0; dt < 8; dt++) {
                    f16x8 v8 = *(const f16x8*)&Vt[cur][(dt * 16 + l16) * VPP + quad * 16 + st2 * 8];
                    f16x4 va = {v8[0], v8[1], v8[2], v8[3]};
                    f16x4 vb = {v8[4], v8[5], v8[6], v8[7]};
                    of[dt] = __builtin_amdgcn_mfma_f32_16x16x16f16(va, pf[st2 * 2], of[dt], 0, 0, 0);
                    of[dt] = __builtin_amdgcn_mfma_f32_16x16x16f16(vb, pf[st2 * 2 + 1], of[dt], 0, 0, 0);
                }
        }

        const float inv = 1.0f / l_i;
        u16* yp = y16 + ((size_t)(b * T + qglob) * NH + h) * HD + quad * 4;
#pragma unroll
        for (int dt = 0; dt < 8; dt++) {
            ushort4 o;
            o.x = (u16)f2bf(of[dt][0] * inv);
            o.y = (u16)f2bf(of[dt][1] * inv);
            o.z = (u16)f2bf(of[dt][2] * inv);
            o.w = (u16)f2bf(of[dt][3] * inv);
            *(ushort4*)(yp + dt * 16) = o;
        }
    }
}

// ---------------------------------------------------------------------------
extern "C" void kernel_launch(void* const* d_in, const int* in_sizes, int n_in,
                              void* d_out, int out_size, void* d_ws, size_t ws_size,
                              hipStream_t stream) {
    const float* x      = (const float*)d_in[0];
    const float* Wq     = (const float*)d_in[1];
    const float* Wk     = (const float*)d_in[2];
    const float* Wv     = (const float*)d_in[3];
    const float* Wp     = (const float*)d_in[4];
    const float* q_gain = (const float*)d_in[5];
    float* out = (float*)d_out;

    const int B = 2;
    const int BT = in_sizes[0] / DIM;      // 4096
    const int T = BT / B;                  // 2048
    const int KD = NKV * HD;               // 512

    u16* x16   = (u16*)d_ws;                        // BT*DIM        (later y16)
    u16* wqkv  = x16 + (size_t)BT * DIM;            // 3072*DIM
    u16* wp16  = wqkv + (size_t)3072 * DIM;         // DIM*DIM
    u16* q16   = wp16 + (size_t)DIM * DIM;          // BT*DIM
    u16* k16   = q16 + (size_t)BT * DIM;            // BT*KD
    u16* vt16  = k16 + (size_t)BT * KD;             // BT*KD
    float* ctab = (float*)(vt16 + (size_t)BT * KD); // T*64
    float* stab = ctab + (size_t)T * 64;            // T*64
    u16* y16   = x16;

    double base = 10000.0;
    if (T > 1024) base = 10000.0 * pow((double)T / 1024.0, 128.0 / 126.0);

    const int nx4  = BT * DIM / 4;
    const int nwq4 = DIM * DIM / 4;
    const int nwk4 = KD * DIM / 4;

    cvt_bf16<<<(nx4 + 255) / 256, 256, 0, stream>>>(x, x16, nx4);
    cvt_bf16<<<(nwq4 + 255) / 256, 256, 0, stream>>>(Wq, wqkv, nwq4);
    cvt_bf16<<<(nwk4 + 255) / 256, 256, 0, stream>>>(Wk, wqkv + (size_t)2048 * DIM, nwk4);
    cvt_bf16<<<(nwk4 + 255) / 256, 256, 0, stream>>>(Wv, wqkv + (size_t)2560 * DIM, nwk4);
    cvt_bf16<<<(nwq4 + 255) / 256, 256, 0, stream>>>(Wp, wp16, nwq4);
    rope_tab<<<T, 64, 0, stream>>>(ctab, stab, base);

    gemm_qkv<<<dim3(BT / 128, 3072 / 128), 256, 0, stream>>>(
        x16, wqkv, q16, k16, vt16, ctab, stab, q_gain, T);

    flash3<<<32 * (T / QT / 2), 256, 0, stream>>>(q16, k16, vt16, y16, T);

    gemm_bf16<<<dim3(BT / 128, DIM / 128), 256, 0, stream>>>(y16, wp16, out, BT, DIM, DIM);
}

// Round 8
// 336.608 us; speedup vs baseline: 20.3065x; 1.1208x over previous
//
#include <hip/hip_runtime.h>
#include <math.h>

#define NH 16
#define NKV 4
#define HD 128
#define DIM 2048
#define GQ 4   // NH/NKV
#define EPS 1.1920928955078125e-07f

typedef unsigned short u16;
using bf16x8 = __attribute__((ext_vector_type(8))) short;
using f16x4  = __attribute__((ext_vector_type(4))) _Float16;
using f32x4  = __attribute__((ext_vector_type(4))) float;

__device__ inline float fast_exp2(float x) { return __builtin_amdgcn_exp2f(x); }

__device__ inline short f2bf(float f) {
    unsigned u = __builtin_bit_cast(unsigned, f);
    return (short)((u + 0x7FFFu + ((u >> 16) & 1u)) >> 16);
}
__device__ inline u16 f2h(float f) {
    _Float16 h = (_Float16)f;
    return __builtin_bit_cast(u16, h);
}

#define ASYNC_LOAD16(g, l)                                                        \
    __builtin_amdgcn_global_load_lds(                                             \
        (const __attribute__((address_space(1))) unsigned*)(g),                   \
        (__attribute__((address_space(3))) unsigned*)(l), 16, 0, 0)

// ---------------- fp32 -> bf16 convert (vectorized) -------------------------
__global__ __launch_bounds__(256) void cvt_bf16(const float* __restrict__ src,
                                                u16* __restrict__ dst, int n4) {
    int i = blockIdx.x * 256 + threadIdx.x;
    if (i < n4) {
        float4 f = ((const float4*)src)[i];
        ushort4 o;
        o.x = (u16)f2bf(f.x); o.y = (u16)f2bf(f.y);
        o.z = (u16)f2bf(f.z); o.w = (u16)f2bf(f.w);
        ((ushort4*)dst)[i] = o;
    }
}

// ---------------- RoPE cos/sin tables: [T][64] ------------------------------
__global__ __launch_bounds__(64) void rope_tab(float* __restrict__ ct,
                                               float* __restrict__ st,
                                               double base) {
    const int t = blockIdx.x;
    const int j = threadIdx.x;
    const float inv_freq = (float)pow(base, -(double)j / 64.0);
    const float fr = (float)t * inv_freq;
    ct[t * 64 + j] = cosf(fr);
    st[t * 64 + j] = sinf(fr);
}

// ------- GEMM (m97 structure): C[M,N] fp32 = A16[M,K] @ W16[N,K]^T ----------
#define GTK 32

__global__ __launch_bounds__(256) void gemm_bf16(const u16* __restrict__ A,
                                                 const u16* __restrict__ W,
                                                 float* __restrict__ C,
                                                 int M, int N, int K) {
    __shared__ u16 As[128 * GTK];
    __shared__ u16 Bs[128 * GTK];
    const int tid = threadIdx.x;
    const int wave = tid >> 6;
    const int lane = tid & 63;
    const int l16 = lane & 15;
    const int quad = lane >> 4;
    const int wm = wave >> 1;
    const int wn = wave & 1;
    const int m0 = blockIdx.x * 128;
    const int n0 = blockIdx.y * 128;

    const int srow = lane >> 2;
    const int scol = (lane & 3) * 8;

    f32x4 acc[4][4];
#pragma unroll
    for (int i = 0; i < 4; i++)
#pragma unroll
        for (int j = 0; j < 4; j++) acc[i][j] = (f32x4){0.f, 0.f, 0.f, 0.f};

    for (int k0 = 0; k0 < K; k0 += GTK) {
        __syncthreads();
#pragma unroll
        for (int j = 0; j < 2; j++) {
            const int rb = wave * 32 + j * 16;
            const u16* ga = A + (size_t)(m0 + rb + srow) * K + k0 + scol;
            const u16* gb = W + (size_t)(n0 + rb + srow) * K + k0 + scol;
            ASYNC_LOAD16(ga, &As[rb * GTK]);
            ASYNC_LOAD16(gb, &Bs[rb * GTK]);
        }
        __syncthreads();

        bf16x8 af[4], bfr[4];
#pragma unroll
        for (int mt = 0; mt < 4; mt++)
            af[mt] = *(const bf16x8*)&As[(wm * 64 + mt * 16 + l16) * GTK + quad * 8];
#pragma unroll
        for (int nt = 0; nt < 4; nt++)
            bfr[nt] = *(const bf16x8*)&Bs[(wn * 64 + nt * 16 + l16) * GTK + quad * 8];
#pragma unroll
        for (int mt = 0; mt < 4; mt++)
#pragma unroll
            for (int nt = 0; nt < 4; nt++)
                acc[mt][nt] = __builtin_amdgcn_mfma_f32_16x16x32_bf16(
                    af[mt], bfr[nt], acc[mt][nt], 0, 0, 0);
    }

#pragma unroll
    for (int mt = 0; mt < 4; mt++)
#pragma unroll
        for (int nt = 0; nt < 4; nt++)
#pragma unroll
            for (int r = 0; r < 4; r++)
                C[(size_t)(m0 + wm * 64 + mt * 16 + quad * 4 + r) * N +
                  n0 + wn * 64 + nt * 16 + l16] = acc[mt][nt][r];
}

// ------- fused QKV GEMM: N=3072 (q 0..2047, k 2048..2559, v 2560..3071) -----
__global__ __launch_bounds__(256) void gemm_qkv(const u16* __restrict__ A,
                                                const u16* __restrict__ W,
                                                u16* __restrict__ q16,
                                                u16* __restrict__ k16,
                                                u16* __restrict__ vt16,
                                                const float* __restrict__ ctab,
                                                const float* __restrict__ stab,
                                                const float* __restrict__ q_gain,
                                                int T) {
    __shared__ u16 As[128 * GTK];
    __shared__ u16 Bs[128 * GTK];
    const int tid = threadIdx.x;
    const int wave = tid >> 6;
    const int lane = tid & 63;
    const int l16 = lane & 15;
    const int quad = lane >> 4;
    const int m0 = blockIdx.x * 128;
    const int n0 = blockIdx.y * 128;
    const int K = DIM;

    const int srow = lane >> 2;
    const int scol = (lane & 3) * 8;

    f32x4 acc[2][8];
#pragma unroll
    for (int i = 0; i < 2; i++)
#pragma unroll
        for (int j = 0; j < 8; j++) acc[i][j] = (f32x4){0.f, 0.f, 0.f, 0.f};

    for (int k0 = 0; k0 < K; k0 += GTK) {
        __syncthreads();
#pragma unroll
        for (int j = 0; j < 2; j++) {
            const int rb = wave * 32 + j * 16;
            const u16* ga = A + (size_t)(m0 + rb + srow) * K + k0 + scol;
            const u16* gb = W + (size_t)(n0 + rb + srow) * K + k0 + scol;
            ASYNC_LOAD16(ga, &As[rb * GTK]);
            ASYNC_LOAD16(gb, &Bs[rb * GTK]);
        }
        __syncthreads();

        bf16x8 af[2], bfr[8];
#pragma unroll
        for (int mt = 0; mt < 2; mt++)
            af[mt] = *(const bf16x8*)&As[(wave * 32 + mt * 16 + l16) * GTK + quad * 8];
#pragma unroll
        for (int nt = 0; nt < 8; nt++)
            bfr[nt] = *(const bf16x8*)&Bs[(nt * 16 + l16) * GTK + quad * 8];
#pragma unroll
        for (int mt = 0; mt < 2; mt++)
#pragma unroll
            for (int nt = 0; nt < 8; nt++)
                acc[mt][nt] = __builtin_amdgcn_mfma_f32_16x16x32_bf16(
                    af[mt], bfr[nt], acc[mt][nt], 0, 0, 0);
    }

    // ---------------- fused epilogue ----------------
    if (n0 < 2048 + 512) {
        const bool isQ = (n0 < 2048);
        // Q: fold gain, 1/sqrt(HD), and log2(e) (flash uses exp2)
        const float gval = isQ ? (q_gain[n0 >> 7] * 0.08838834764831843f * 1.4426950408889634f)
                               : 1.0f;
        float ss[2][4];
#pragma unroll
        for (int mt = 0; mt < 2; mt++)
#pragma unroll
            for (int r = 0; r < 4; r++) {
                float s = 0.f;
#pragma unroll
                for (int nt = 0; nt < 8; nt++) {
                    float a = acc[mt][nt][r];
                    s = fmaf(a, a, s);
                }
                s += __shfl_xor(s, 1);
                s += __shfl_xor(s, 2);
                s += __shfl_xor(s, 4);
                s += __shfl_xor(s, 8);
                ss[mt][r] = s;
            }
#pragma unroll
        for (int mt = 0; mt < 2; mt++)
#pragma unroll
            for (int r = 0; r < 4; r++) {
                const float scale = rsqrtf(ss[mt][r] * (1.0f / HD) + EPS) * gval;
                const int m = m0 + wave * 32 + mt * 16 + quad * 4 + r;
                const int t = m & (T - 1);
                const float* ct = ctab + t * 64;
                const float* st = stab + t * 64;
                u16* dst = isQ ? (q16 + (size_t)m * 2048 + n0)
                               : (k16 + (size_t)m * 512 + (n0 - 2048));
#pragma unroll
                for (int nt = 0; nt < 4; nt++) {
                    const int j = nt * 16 + l16;
                    const float c = ct[j], s = st[j];
                    const float x1 = acc[mt][nt][r] * scale;
                    const float x2 = acc[mt][nt + 4][r] * scale;
                    dst[j]      = (u16)f2bf(x1 * c + x2 * s);
                    dst[j + 64] = (u16)f2bf(x2 * c - x1 * s);
                }
            }
    } else {
        const int kvh = (n0 - 2560) >> 7;
#pragma unroll
        for (int mt = 0; mt < 2; mt++) {
            const int mb = m0 + wave * 32 + mt * 16 + quad * 4;
            const int b = mb / 2048;          // T == 2048
            const int t0 = mb & (T - 1);
#pragma unroll
            for (int nt = 0; nt < 8; nt++) {
                const int d = nt * 16 + l16;
                ushort4 o;
                o.x = f2h(acc[mt][nt][0]);
                o.y = f2h(acc[mt][nt][1]);
                o.z = f2h(acc[mt][nt][2]);
                o.w = f2h(acc[mt][nt][3]);
                *(ushort4*)(vt16 + ((size_t)((b * NKV + kvh) * HD + d)) * T + t0) = o;
            }
        }
    }
}

// ------ flash attention v4: DMA-staged double buffer, XOR-swizzled LDS ------
// S^T = K Q^T (bf16 x32); softmax in registers (exp2); O^T = V^T P^T (f16 x16)
// K tile: 64 rows x 128 bf16 (256B/row, 16 chunks of 16B, chunk c at phys c^(r&15))
// V tile: 128 rows x 64 f16  (128B/row,  8 chunks of 16B, chunk c at phys c^(d&7))
#define QT 64
#define SK 64

__global__ __launch_bounds__(256) void flash4(const u16* __restrict__ q16,
                                              const u16* __restrict__ k16,
                                              const u16* __restrict__ vt16,
                                              u16* __restrict__ y16, int T) {
    __shared__ u16 Ks[2][SK * 128];
    __shared__ u16 Vt[2][HD * 64];

    const int tid = threadIdx.x;
    const int wave = tid >> 6;
    const int lane = tid & 63;
    const int l16 = lane & 15;
    const int quad = lane >> 4;

    const int bid = blockIdx.x;
    const int bh = bid & 31;          // b*NH + h
    const int pr = bid >> 5;          // pair index 0..T/QT/2-1
    const int h = bh & 15;
    const int b = bh >> 4;
    const int kv = h / GQ;

    const u16* kg = k16 + ((size_t)b * T * NKV + kv) * HD;
    const u16* vg = vt16 + (size_t)(b * NKV + kv) * HD * T;

    // DMA source offsets (per-thread, fixed): seg = wave*4 + j
    // K: lane covers row seg*4 + (lane>>4), phys chunk lane&15
    const int krow_in_seg = lane >> 4;          // 0..3
    const int kclog_base = lane & 15;           // phys chunk; logical = phys ^ (r&15)
    // V: lane covers row seg*8 + (lane>>3), phys chunk lane&7
    const int vrow_in_seg = lane >> 3;          // 0..7
    const int vclog = (lane & 7) ^ (lane >> 3); // logical chunk (d&7 == lane>>3)

#pragma unroll 1
    for (int half = 0; half < 2; half++) {
        const int qt = half ? (T / QT - 1 - pr) : pr;
        const int q0 = qt * QT;
        const int qglob = q0 + wave * 16 + l16;
        const int nts = q0 / SK + 1;

        // Q^T B-fragments (gain, 1/sqrt(HD), log2e folded in)
        bf16x8 qf[4];
        {
            const u16* qp = q16 + ((size_t)(b * T + qglob) * NH + h) * HD;
#pragma unroll
            for (int kc = 0; kc < 4; kc++)
                qf[kc] = *(const bf16x8*)(qp + kc * 32 + quad * 8);
        }

        f32x4 of[8];
#pragma unroll
        for (int i = 0; i < 8; i++) of[i] = (f32x4){0.f, 0.f, 0.f, 0.f};
        float m_i = -1e30f, l_i = 0.0f;

        // make sure previous half's readers of buf0 are done, then preload tile 0
        __syncthreads();
#pragma unroll
        for (int j = 0; j < 4; j++) {
            const int seg = wave * 4 + j;
            const int r = seg * 4 + krow_in_seg;
            const int clog = kclog_base ^ (r & 15);
            ASYNC_LOAD16(kg + (size_t)r * (NKV * HD) + clog * 8, &Ks[0][seg * 512]);
            const int d = seg * 8 + vrow_in_seg;
            ASYNC_LOAD16(vg + (size_t)d * T + vclog * 8, &Vt[0][seg * 512]);
        }

        for (int it = 0; it < nts; it++) {
            const int cur = it & 1;
            __syncthreads();   // drains DMA for tile `it` (in flight one full phase)

            // issue DMA for tile it+1 into the other buffer (readers of it-1 done)
            if (it + 1 < nts) {
                const int s1 = (it + 1) * SK;
#pragma unroll
                for (int j = 0; j < 4; j++) {
                    const int seg = wave * 4 + j;
                    const int r = seg * 4 + krow_in_seg;
                    const int clog = kclog_base ^ (r & 15);
                    ASYNC_LOAD16(kg + (size_t)(s1 + r) * (NKV * HD) + clog * 8,
                                 &Ks[cur ^ 1][seg * 512]);
                    const int d = seg * 8 + vrow_in_seg;
                    ASYNC_LOAD16(vg + (size_t)d * T + s1 + vclog * 8,
                                 &Vt[cur ^ 1][seg * 512]);
                }
            }

            // S^T = K Q^T
            f32x4 sf[4];
#pragma unroll
            for (int st = 0; st < 4; st++) sf[st] = (f32x4){0.f, 0.f, 0.f, 0.f};
#pragma unroll
            for (int kc = 0; kc < 4; kc++)
#pragma unroll
                for (int st = 0; st < 4; st++) {
                    const int row = st * 16 + l16;
                    bf16x8 kf = *(const bf16x8*)
                        &Ks[cur][row * 128 + (((kc * 4 + quad) ^ l16) * 8)];
                    sf[st] = __builtin_amdgcn_mfma_f32_16x16x32_bf16(kf, qf[kc], sf[st], 0, 0, 0);
                }

            if (it == nts - 1) {  // diagonal tile: causal mask
#pragma unroll
                for (int st = 0; st < 4; st++)
#pragma unroll
                    for (int r = 0; r < 4; r++)
                        if (q0 + st * 16 + quad * 4 + r > qglob) sf[st][r] = -1e30f;
            }

            float tm = -1e30f;
#pragma unroll
            for (int st = 0; st < 4; st++)
#pragma unroll
                for (int r = 0; r < 4; r++) tm = fmaxf(tm, sf[st][r]);
            tm = fmaxf(tm, __shfl_xor(tm, 16));
            tm = fmaxf(tm, __shfl_xor(tm, 32));

            const float mprev = m_i;
            const float mnew = fmaxf(mprev, tm);
            m_i = mnew;
            const float alpha = fast_exp2(mprev - mnew);

            f16x4 pf[4];
            float ls = 0.0f;
#pragma unroll
            for (int st = 0; st < 4; st++)
#pragma unroll
                for (int r = 0; r < 4; r++) {
                    float e = fast_exp2(sf[st][r] - mnew);
                    ls += e;
                    pf[st][r] = (_Float16)e;
                }
            ls += __shfl_xor(ls, 16);
            ls += __shfl_xor(ls, 32);
            l_i = alpha * l_i + ls;

            if (__ballot(mnew > mprev)) {
#pragma unroll
                for (int dt = 0; dt < 8; dt++)
#pragma unroll
                    for (int r = 0; r < 4; r++) of[dt][r] *= alpha;
            }

            // O^T += V^T P^T  (V^T A-frag: row d, logical shorts st*16+quad*4..+3)
#pragma unroll
            for (int st = 0; st < 4; st++) {
                const int clog = st * 2 + (quad >> 1);
#pragma unroll
                for (int dt = 0; dt < 8; dt++) {
                    const int d = dt * 16 + l16;
                    const int phys = clog ^ (l16 & 7);
                    f16x4 va = *(const f16x4*)
                        &Vt[cur][d * 64 + phys * 8 + (quad & 1) * 4];
                    of[dt] = __builtin_amdgcn_mfma_f32_16x16x16f16(va, pf[st], of[dt], 0, 0, 0);
                }
            }
        }

        const float inv = 1.0f / l_i;
        u16* yp = y16 + ((size_t)(b * T + qglob) * NH + h) * HD + quad * 4;
#pragma unroll
        for (int dt = 0; dt < 8; dt++) {
            ushort4 o;
            o.x = (u16)f2bf(of[dt][0] * inv);
            o.y = (u16)f2bf(of[dt][1] * inv);
            o.z = (u16)f2bf(of[dt][2] * inv);
            o.w = (u16)f2bf(of[dt][3] * inv);
            *(ushort4*)(yp + dt * 16) = o;
        }
    }
}

// ---------------------------------------------------------------------------
extern "C" void kernel_launch(void* const* d_in, const int* in_sizes, int n_in,
                              void* d_out, int out_size, void* d_ws, size_t ws_size,
                              hipStream_t stream) {
    const float* x      = (const float*)d_in[0];
    const float* Wq     = (const float*)d_in[1];
    const float* Wk     = (const float*)d_in[2];
    const float* Wv     = (const float*)d_in[3];
    const float* Wp     = (const float*)d_in[4];
    const float* q_gain = (const float*)d_in[5];
    float* out = (float*)d_out;

    const int B = 2;
    const int BT = in_sizes[0] / DIM;      // 4096
    const int T = BT / B;                  // 2048
    const int KD = NKV * HD;               // 512

    u16* x16   = (u16*)d_ws;                        // BT*DIM        (later y16)
    u16* wqkv  = x16 + (size_t)BT * DIM;            // 3072*DIM
    u16* wp16  = wqkv + (size_t)3072 * DIM;         // DIM*DIM
    u16* q16   = wp16 + (size_t)DIM * DIM;          // BT*DIM
    u16* k16   = q16 + (size_t)BT * DIM;            // BT*KD
    u16* vt16  = k16 + (size_t)BT * KD;             // BT*KD
    float* ctab = (float*)(vt16 + (size_t)BT * KD); // T*64
    float* stab = ctab + (size_t)T * 64;            // T*64
    u16* y16   = x16;

    double base = 10000.0;
    if (T > 1024) base = 10000.0 * pow((double)T / 1024.0, 128.0 / 126.0);

    const int nx4  = BT * DIM / 4;
    const int nwq4 = DIM * DIM / 4;
    const int nwk4 = KD * DIM / 4;

    cvt_bf16<<<(nx4 + 255) / 256, 256, 0, stream>>>(x, x16, nx4);
    cvt_bf16<<<(nwq4 + 255) / 256, 256, 0, stream>>>(Wq, wqkv, nwq4);
    cvt_bf16<<<(nwk4 + 255) / 256, 256, 0, stream>>>(Wk, wqkv + (size_t)2048 * DIM, nwk4);
    cvt_bf16<<<(nwk4 + 255) / 256, 256, 0, stream>>>(Wv, wqkv + (size_t)2560 * DIM, nwk4);
    cvt_bf16<<<(nwq4 + 255) / 256, 256, 0, stream>>>(Wp, wp16, nwq4);
    rope_tab<<<T, 64, 0, stream>>>(ctab, stab, base);

    gemm_qkv<<<dim3(BT / 128, 3072 / 128), 256, 0, stream>>>(
        x16, wqkv, q16, k16, vt16, ctab, stab, q_gain, T);

    flash4<<<32 * (T / QT / 2), 256, 0, stream>>>(q16, k16, vt16, y16, T);

    gemm_bf16<<<dim3(BT / 128, DIM / 128), 256, 0, stream>>>(y16, wp16, out, BT, DIM, DIM);
}